// Round 1
// baseline (4716.748 us; speedup 1.0000x reference)
//
#include <hip/hip_runtime.h>
#include <math.h>

#define NB 8
#define D 512
#define H 8
#define DH 64
#define NSEG 16
#define RT 64
#define UU 256
#define QN 336
#define KN 335
#define SROWS 320
#define FFN_D 2048
#define LAYERS 8
#define OUTD 1024
#define TR 260
#define NEGV (-100000000.0f)
#define QSCALE 0.125f

// ---------------- lr + max ----------------
__global__ void lr_k(const int* __restrict__ lengths, int* __restrict__ lrw,
                     float* __restrict__ out_lr) {
    if (threadIdx.x == 0) {
        int mx = 0;
        for (int b = 0; b < NB; ++b) {
            int v = lengths[b] >> 2;
            lrw[b] = v;
            out_lr[b] = (float)v;
            if (v > mx) mx = v;
        }
        lrw[NB] = mx;
    }
}

// ---------------- input projection + reshape to (t,b,512) ----------------
__global__ __launch_bounds__(128) void inproj_k(const float* __restrict__ input,
                                                const float* __restrict__ w_in,
                                                float* __restrict__ XB) {
    __shared__ float wl[80 * 128];
    __shared__ float il[4 * 80];
    int tid = threadIdx.x;
    int t = blockIdx.x >> 3;
    int b = blockIdx.x & 7;
    for (int i = tid; i < 80 * 128; i += 128) wl[i] = w_in[i];
    const float* inp = input + ((size_t)b * 1040 + (size_t)t * 4) * 80;
    for (int i = tid; i < 320; i += 128) il[i] = inp[i];
    __syncthreads();
    float* xrow = XB + ((size_t)(t * NB + b)) * D;
#pragma unroll
    for (int c = 0; c < 4; ++c) {
        float acc = 0.f;
        for (int i = 0; i < 80; ++i) acc = fmaf(il[c * 80 + i], wl[i * 128 + tid], acc);
        xrow[c * 128 + tid] = acc;
    }
}

// ---------------- init state S = [rc(64), utt(256)] ----------------
__global__ __launch_bounds__(256) void initstate_k(const float* __restrict__ XB,
                                                   float* __restrict__ S) {
    int r = blockIdx.x;  // (srow, b)
    int srow = r >> 3, b = r & 7;
    int src;
    if (srow < RT) {
        int i = srow >> 2, jj = srow & 3;
        src = (i < 15 ? (i + 1) * 16 : 256) + jj;
    } else {
        src = srow - RT;
    }
    const float* xr = XB + ((size_t)(src * NB + b)) * D;
    float* sr = S + (size_t)r * D;
    sr[threadIdx.x] = xr[threadIdx.x];
    sr[threadIdx.x + 256] = xr[threadIdx.x + 256];
}

// ---------------- initial mems (segment means of utt) ----------------
__global__ __launch_bounds__(256) void mems0_k(const float* __restrict__ XB,
                                               float* __restrict__ MEMS) {
    int ib = blockIdx.x;  // i*8+b, i<15
    int i = ib >> 3, b = ib & 7;
    for (int c = 0; c < 2; ++c) {
        int col = threadIdx.x + c * 256;
        float s = 0.f;
#pragma unroll
        for (int t = 0; t < 16; ++t) s += XB[((size_t)((i * 16 + t) * NB + b)) * D + col];
        MEMS[(size_t)ib * D + col] = s * (1.f / 16.f);
    }
}

// ---------------- LayerNorm (one block per row) ----------------
template <int WIDTH>
__global__ __launch_bounds__(256) void ln_k(const float* __restrict__ X, float* __restrict__ Y,
                                            const float* __restrict__ g,
                                            const float* __restrict__ be) {
    constexpr int VPT = WIDTH / 256;
    int row = blockIdx.x;
    const float* x = X + (size_t)row * WIDTH;
    float v[VPT];
    float s = 0.f, ss = 0.f;
#pragma unroll
    for (int j = 0; j < VPT; ++j) {
        v[j] = x[threadIdx.x + j * 256];
        s += v[j];
        ss = fmaf(v[j], v[j], ss);
    }
#pragma unroll
    for (int off = 32; off; off >>= 1) {
        s += __shfl_xor(s, off);
        ss += __shfl_xor(ss, off);
    }
    __shared__ float rs_[4], rss_[4];
    int w = threadIdx.x >> 6;
    if ((threadIdx.x & 63) == 0) {
        rs_[w] = s;
        rss_[w] = ss;
    }
    __syncthreads();
    s = rs_[0] + rs_[1] + rs_[2] + rs_[3];
    ss = rss_[0] + rss_[1] + rss_[2] + rss_[3];
    float mean = s * (1.f / WIDTH);
    float var = ss * (1.f / WIDTH) - mean * mean;
    float rstd = rsqrtf(var + 1e-5f);
    float* y = Y + (size_t)row * WIDTH;
#pragma unroll
    for (int j = 0; j < VPT; ++j) {
        int col = threadIdx.x + j * 256;
        y[col] = (v[j] - mean) * rstd * g[col] + be[col];
    }
}

// ---------------- summary = per-segment mean of ln_utt ----------------
__global__ __launch_bounds__(256) void summary_k(const float* __restrict__ LN,
                                                 float* __restrict__ SUM) {
    int ib = blockIdx.x;  // i*8+b
    int i = ib >> 3, b = ib & 7;
    for (int c = 0; c < 2; ++c) {
        int col = threadIdx.x + c * 256;
        float s = 0.f;
#pragma unroll
        for (int t = 0; t < 16; ++t)
            s += LN[((size_t)((RT + i * 16 + t) * NB + b)) * D + col];
        SUM[(size_t)ib * D + col] = s * (1.f / 16.f);
    }
}

// ---------------- fp32 tiled GEMM: C = A(MxK) @ W(KxN) + bias ----------------
// flags: 1 = relu, 2 = add into existing C
__global__ __launch_bounds__(256) void gemm_k(const float* __restrict__ A,
                                              const float* __restrict__ W,
                                              const float* __restrict__ bias,
                                              float* __restrict__ C, int M, int N, int Kd,
                                              int flags) {
    __shared__ float As[16][68];
    __shared__ float Ws[16][64];
    int tid = threadIdx.x;
    int tx = tid & 15, ty = tid >> 4;
    int n0 = blockIdx.x * 64, m0 = blockIdx.y * 64;
    float acc[4][4] = {};
    for (int k0 = 0; k0 < Kd; k0 += 16) {
        {
            int k = tid & 15, mb = tid >> 4;
#pragma unroll
            for (int r = 0; r < 4; ++r) {
                int mm = mb + r * 16;
                int row = m0 + mm;
                As[k][mm] = (row < M) ? A[(size_t)row * Kd + k0 + k] : 0.f;
            }
        }
        {
            int n = tid & 63, kb = tid >> 6;
#pragma unroll
            for (int r = 0; r < 4; ++r) {
                int kk = kb + r * 4;
                Ws[kk][n] = W[(size_t)(k0 + kk) * N + n0 + n];
            }
        }
        __syncthreads();
#pragma unroll
        for (int kk = 0; kk < 16; ++kk) {
            const float4 a = *(const float4*)&As[kk][ty * 4];
            const float4 b = *(const float4*)&Ws[kk][tx * 4];
            const float am[4] = {a.x, a.y, a.z, a.w};
            const float bn[4] = {b.x, b.y, b.z, b.w};
#pragma unroll
            for (int mi = 0; mi < 4; ++mi)
#pragma unroll
                for (int ni = 0; ni < 4; ++ni) acc[mi][ni] = fmaf(am[mi], bn[ni], acc[mi][ni]);
        }
        __syncthreads();
    }
#pragma unroll
    for (int mi = 0; mi < 4; ++mi) {
        int row = m0 + ty * 4 + mi;
        if (row >= M) continue;
#pragma unroll
        for (int ni = 0; ni < 4; ++ni) {
            int col = n0 + tx * 4 + ni;
            float v = acc[mi][ni] + bias[col];
            if (flags & 1) v = fmaxf(v, 0.f);
            if (flags & 2) v += C[(size_t)row * N + col];
            C[(size_t)row * N + col] = v;
        }
    }
}

// ---------------- attention: one wave per (qrow, b, h); only allowed keys ----------------
__global__ __launch_bounds__(64) void attn_k(const float* __restrict__ Q,
                                             const float* __restrict__ K,
                                             const float* __restrict__ V,
                                             float* __restrict__ ATT,
                                             const int* __restrict__ lrw) {
    int lane = threadIdx.x;
    int qrow = blockIdx.x;
    int bh = blockIdx.y;
    int b = bh >> 3, h = bh & 7;

    int i, is_sum;
    if (qrow < RT) {
        i = qrow >> 2;
        is_sum = 0;
    } else if (qrow < RT + UU) {
        i = (qrow - RT) >> 4;
        is_sum = 0;
    } else {
        i = qrow - (RT + UU);
        is_sum = 1;
    }
    int ms = (i > 4) ? (i - 4) : 0;
    int n_mem = is_sum ? 0 : (i - ms);
    int us = (i * 16 - 32 > 0) ? (i * 16 - 32) : 0;
    int ue = (i + 1) * 16;
    int total = n_mem + 4 + (ue - us);
    int klen = KN + lrw[b] - lrw[NB];

    __shared__ float qs[64];
    __shared__ float ps[64];
    __shared__ int kks[64];
    qs[lane] = Q[((size_t)(qrow * NB + b)) * D + h * DH + lane] * QSCALE;
    __syncthreads();

    int kk = -1;
    if (lane < total) {
        if (lane < n_mem)
            kk = ms + lane;
        else if (lane < n_mem + 4)
            kk = 15 + i * 4 + (lane - n_mem);
        else
            kk = 79 + us + (lane - n_mem - 4);
    }
    float s = NEGV;
    if (kk >= 0 && kk < klen) {
        const float4* kr = (const float4*)&K[((size_t)(kk * NB + b)) * D + h * DH];
        const float4* qq = (const float4*)qs;
        float acc = 0.f;
#pragma unroll
        for (int d4 = 0; d4 < 16; ++d4) {
            float4 kv = kr[d4];
            float4 qv = qq[d4];
            acc = fmaf(kv.x, qv.x, acc);
            acc = fmaf(kv.y, qv.y, acc);
            acc = fmaf(kv.z, qv.z, acc);
            acc = fmaf(kv.w, qv.w, acc);
        }
        s = acc;
    }
    float m = s;
#pragma unroll
    for (int off = 32; off; off >>= 1) m = fmaxf(m, __shfl_xor(m, off));
    float p = __expf(s - m);
    float sum = p;
#pragma unroll
    for (int off = 32; off; off >>= 1) sum += __shfl_xor(sum, off);
    float inv = 1.f / sum;
    ps[lane] = p * inv;
    kks[lane] = kk;
    __syncthreads();

    float acc = 0.f;
    for (int j = 0; j < total; ++j) {
        int kkj = kks[j];
        acc = fmaf(ps[j], V[((size_t)(kkj * NB + b)) * D + h * DH + lane], acc);
    }
    ATT[((size_t)(qrow * NB + b)) * D + h * DH + lane] = acc;
}

// ---------------- residual add + new mems = tanh(summary out) ----------------
__global__ __launch_bounds__(256) void fuse_k(const float* __restrict__ OUTB,
                                              float* __restrict__ S, float* __restrict__ MEMS) {
    int idx = blockIdx.x * 256 + threadIdx.x;
    const int total1 = SROWS * NB * D;
    const int total2 = 15 * NB * D;
    if (idx < total1) {
        S[idx] += OUTB[idx];
    } else if (idx < total1 + total2) {
        int j = idx - total1;
        MEMS[j] = tanhf(OUTB[total1 + j]);
    }
}

// ---------------- final LN (width 1024) with permuted output ----------------
__global__ __launch_bounds__(256) void final_ln_k(const float* __restrict__ Yb,
                                                  const float* __restrict__ g,
                                                  const float* __restrict__ be,
                                                  float* __restrict__ out) {
    int row = blockIdx.x;  // u*8+b
    int u = row >> 3, b = row & 7;
    const float* x = Yb + (size_t)row * OUTD;
    float v[4];
    float s = 0.f, ss = 0.f;
#pragma unroll
    for (int j = 0; j < 4; ++j) {
        v[j] = x[threadIdx.x + j * 256];
        s += v[j];
        ss = fmaf(v[j], v[j], ss);
    }
#pragma unroll
    for (int off = 32; off; off >>= 1) {
        s += __shfl_xor(s, off);
        ss += __shfl_xor(ss, off);
    }
    __shared__ float rs_[4], rss_[4];
    int w = threadIdx.x >> 6;
    if ((threadIdx.x & 63) == 0) {
        rs_[w] = s;
        rss_[w] = ss;
    }
    __syncthreads();
    s = rs_[0] + rs_[1] + rs_[2] + rs_[3];
    ss = rss_[0] + rss_[1] + rss_[2] + rss_[3];
    float mean = s * (1.f / OUTD);
    float var = ss * (1.f / OUTD) - mean * mean;
    float rstd = rsqrtf(var + 1e-5f);
    float* o = out + ((size_t)(b * 256 + u)) * OUTD;
#pragma unroll
    for (int j = 0; j < 4; ++j) {
        int col = threadIdx.x + j * 256;
        o[col] = (v[j] - mean) * rstd * g[col] + be[col];
    }
}

extern "C" void kernel_launch(void* const* d_in, const int* in_sizes, int n_in, void* d_out,
                              int out_size, void* d_ws, size_t ws_size, hipStream_t stream) {
    (void)in_sizes;
    (void)n_in;
    (void)out_size;
    (void)ws_size;
    const float* input = (const float*)d_in[0];
    const int* lengths = (const int*)d_in[1];
    const float* w_in = (const float*)d_in[2];
    const float* ln_in_g = (const float*)d_in[3];
    const float* ln_in_b = (const float*)d_in[4];
    const float* wq = (const float*)d_in[5];
    const float* bq = (const float*)d_in[6];
    const float* wk = (const float*)d_in[7];
    const float* bk = (const float*)d_in[8];
    const float* wv = (const float*)d_in[9];
    const float* bv = (const float*)d_in[10];
    const float* wo = (const float*)d_in[11];
    const float* bo = (const float*)d_in[12];
    const float* ff_g = (const float*)d_in[13];
    const float* ff_b = (const float*)d_in[14];
    const float* w1 = (const float*)d_in[15];
    const float* b1 = (const float*)d_in[16];
    const float* w2 = (const float*)d_in[17];
    const float* b2 = (const float*)d_in[18];
    const float* lo_g = (const float*)d_in[19];
    const float* lo_b = (const float*)d_in[20];
    const float* w_out = (const float*)d_in[21];
    const float* b_out = (const float*)d_in[22];
    const float* lng = (const float*)d_in[23];
    const float* lnb = (const float*)d_in[24];
    float* out = (float*)d_out;

    float* ws = (float*)d_ws;
    size_t o = 0;
    // [MEMS][LNB][SUMB] contiguous => kin = MEMS base (2680 rows), qin = LNB base (2688 rows)
    float* MEMS = ws + o; o += (size_t)15 * NB * D;
    float* LNB  = ws + o; o += (size_t)SROWS * NB * D;
    float* SUMB = ws + o; o += (size_t)NSEG * NB * D;
    (void)SUMB;
    float* SB   = ws + o; o += (size_t)SROWS * NB * D;
    float* QB   = ws + o; o += (size_t)QN * NB * D;
    float* KB   = ws + o; o += (size_t)KN * NB * D;
    float* VB   = ws + o; o += (size_t)KN * NB * D;
    float* ATTB = ws + o; o += (size_t)QN * NB * D;
    float* HB   = ws + o; o += (size_t)SROWS * NB * FFN_D;
    int* LRW = (int*)(ws + o); o += 16;
    float* OUTB = QB;   // alias: QB free after attention
    float* XB = ATTB;   // alias: ATTB free during init

    lr_k<<<1, 64, 0, stream>>>(lengths, LRW, out + (size_t)NB * 256 * 1024);
    inproj_k<<<TR * NB, 128, 0, stream>>>(input, w_in, XB);
    initstate_k<<<SROWS * NB, 256, 0, stream>>>(XB, SB);
    mems0_k<<<15 * NB, 256, 0, stream>>>(XB, MEMS);

    auto gemm = [&](const float* A, const float* W, const float* bias, float* C, int M, int N,
                    int Kd, int flags) {
        dim3 g(N / 64, (M + 63) / 64);
        gemm_k<<<g, 256, 0, stream>>>(A, W, bias, C, M, N, Kd, flags);
    };

    for (int l = 0; l < LAYERS; ++l) {
        ln_k<512><<<SROWS * NB, 256, 0, stream>>>(SB, LNB, ln_in_g + l * D, ln_in_b + l * D);
        summary_k<<<NSEG * NB, 256, 0, stream>>>(LNB, SUMB);
        gemm(LNB, wq + (size_t)l * D * D, bq + l * D, QB, QN * NB, D, D, 0);
        gemm(MEMS, wk + (size_t)l * D * D, bk + l * D, KB, KN * NB, D, D, 0);
        gemm(MEMS, wv + (size_t)l * D * D, bv + l * D, VB, KN * NB, D, D, 0);
        attn_k<<<dim3(QN, NB * H), 64, 0, stream>>>(QB, KB, VB, ATTB, LRW);
        gemm(ATTB, wo + (size_t)l * D * D, bo + l * D, OUTB, QN * NB, D, D, 0);
        fuse_k<<<(SROWS * NB * D + 15 * NB * D) / 256, 256, 0, stream>>>(OUTB, SB, MEMS);
        ln_k<512><<<SROWS * NB, 256, 0, stream>>>(SB, LNB, ff_g + l * D, ff_b + l * D);
        gemm(LNB, w1 + (size_t)l * D * FFN_D, b1 + l * FFN_D, HB, SROWS * NB, FFN_D, D, 1);
        gemm(HB, w2 + (size_t)l * FFN_D * D, b2 + l * D, SB, SROWS * NB, D, FFN_D, 2);
        ln_k<512><<<SROWS * NB, 256, 0, stream>>>(SB, SB, lo_g + l * D, lo_b + l * D);
    }
    // final projection of utt rows (SB rows 64..319) then LN -> out
    gemm(SB + (size_t)RT * NB * D, w_out, b_out, HB, UU * NB, OUTD, D, 0);
    final_ln_k<<<UU * NB, 256, 0, stream>>>(HB, lng, lnb, out);
}

// Round 2
// 1801.033 us; speedup vs baseline: 2.6189x; 2.6189x over previous
//
#include <hip/hip_runtime.h>
#include <math.h>

#define NB 8
#define D 512
#define H 8
#define DH 64
#define NSEG 16
#define RT 64
#define UU 256
#define QN 336
#define KN 335
#define SROWS 320
#define FFN_D 2048
#define LAYERS 8
#define OUTD 1024
#define TR 260
#define NEGV (-100000000.0f)
#define QSCALE 0.125f

typedef __attribute__((ext_vector_type(8))) short bf16x8;
typedef __attribute__((ext_vector_type(4))) float f32x4;

__device__ inline unsigned short f2bf(float f) {
    union { float f; unsigned int u; } v; v.f = f;
    unsigned int u = v.u;
    unsigned int r = (u + 0x7FFFu + ((u >> 16) & 1u)) >> 16;
    return (unsigned short)r;
}
__device__ inline float bf2f(unsigned short h) {
    union { unsigned int u; float f; } v; v.u = ((unsigned int)h) << 16;
    return v.f;
}

// ---------------- lr + max ----------------
__global__ void lr_k(const int* __restrict__ lengths, int* __restrict__ lrw,
                     float* __restrict__ out_lr) {
    if (threadIdx.x == 0) {
        int mx = 0;
        for (int b = 0; b < NB; ++b) {
            int v = lengths[b] >> 2;
            lrw[b] = v;
            out_lr[b] = (float)v;
            if (v > mx) mx = v;
        }
        lrw[NB] = mx;
    }
}

// ---------------- input projection + reshape to (t,b,512) ----------------
__global__ __launch_bounds__(128) void inproj_k(const float* __restrict__ input,
                                                const float* __restrict__ w_in,
                                                float* __restrict__ XB) {
    __shared__ float wl[80 * 128];
    __shared__ float il[4 * 80];
    int tid = threadIdx.x;
    int t = blockIdx.x >> 3;
    int b = blockIdx.x & 7;
    for (int i = tid; i < 80 * 128; i += 128) wl[i] = w_in[i];
    const float* inp = input + ((size_t)b * 1040 + (size_t)t * 4) * 80;
    for (int i = tid; i < 320; i += 128) il[i] = inp[i];
    __syncthreads();
    float* xrow = XB + ((size_t)(t * NB + b)) * D;
#pragma unroll
    for (int c = 0; c < 4; ++c) {
        float acc = 0.f;
        for (int i = 0; i < 80; ++i) acc = fmaf(il[c * 80 + i], wl[i * 128 + tid], acc);
        xrow[c * 128 + tid] = acc;
    }
}

// ---------------- init state S = [rc(64), utt(256)] (fp32) ----------------
__global__ __launch_bounds__(256) void initstate_k(const float* __restrict__ XB,
                                                   float* __restrict__ S) {
    int r = blockIdx.x;
    int srow = r >> 3, b = r & 7;
    int src;
    if (srow < RT) {
        int i = srow >> 2, jj = srow & 3;
        src = (i < 15 ? (i + 1) * 16 : 256) + jj;
    } else {
        src = srow - RT;
    }
    const float* xr = XB + ((size_t)(src * NB + b)) * D;
    float* sr = S + (size_t)r * D;
    sr[threadIdx.x] = xr[threadIdx.x];
    sr[threadIdx.x + 256] = xr[threadIdx.x + 256];
}

// ---------------- initial mems -> bf16 ----------------
__global__ __launch_bounds__(256) void mems0_k(const float* __restrict__ XB,
                                               unsigned short* __restrict__ MEMS) {
    int ib = blockIdx.x;
    int i = ib >> 3, b = ib & 7;
    for (int c = 0; c < 2; ++c) {
        int col = threadIdx.x + c * 256;
        float s = 0.f;
#pragma unroll
        for (int t = 0; t < 16; ++t) s += XB[((size_t)((i * 16 + t) * NB + b)) * D + col];
        MEMS[(size_t)ib * D + col] = f2bf(s * (1.f / 16.f));
    }
}

// ---------------- LayerNorm: fp32 in, bf16 out (+optional fp32 out) ----------------
__global__ __launch_bounds__(256) void ln_k(const float* __restrict__ X,
                                            unsigned short* __restrict__ Y16,
                                            float* __restrict__ Yf,
                                            const float* __restrict__ g,
                                            const float* __restrict__ be, int dual) {
    int row = blockIdx.x;
    const float* x = X + (size_t)row * D;
    float v[2];
    float s = 0.f, ss = 0.f;
#pragma unroll
    for (int j = 0; j < 2; ++j) {
        v[j] = x[threadIdx.x + j * 256];
        s += v[j];
        ss = fmaf(v[j], v[j], ss);
    }
#pragma unroll
    for (int off = 32; off; off >>= 1) {
        s += __shfl_xor(s, off);
        ss += __shfl_xor(ss, off);
    }
    __shared__ float rs_[4], rss_[4];
    int w = threadIdx.x >> 6;
    if ((threadIdx.x & 63) == 0) {
        rs_[w] = s;
        rss_[w] = ss;
    }
    __syncthreads();
    s = rs_[0] + rs_[1] + rs_[2] + rs_[3];
    ss = rss_[0] + rss_[1] + rss_[2] + rss_[3];
    float mean = s * (1.f / D);
    float var = ss * (1.f / D) - mean * mean;
    float rstd = rsqrtf(var + 1e-5f);
#pragma unroll
    for (int j = 0; j < 2; ++j) {
        int col = threadIdx.x + j * 256;
        float y = (v[j] - mean) * rstd * g[col] + be[col];
        Y16[(size_t)row * D + col] = f2bf(y);
        if (dual) Yf[(size_t)row * D + col] = y;
    }
}

// ---------------- summary = per-segment mean of ln_utt (bf16) ----------------
__global__ __launch_bounds__(256) void summary_k(const unsigned short* __restrict__ LN16,
                                                 unsigned short* __restrict__ SUM16) {
    int ib = blockIdx.x;
    int i = ib >> 3, b = ib & 7;
    for (int c = 0; c < 2; ++c) {
        int col = threadIdx.x + c * 256;
        float s = 0.f;
#pragma unroll
        for (int t = 0; t < 16; ++t)
            s += bf2f(LN16[((size_t)((RT + i * 16 + t) * NB + b)) * D + col]);
        SUM16[(size_t)ib * D + col] = f2bf(s * (1.f / 16.f));
    }
}

// ---------------- 32x32 transpose + fp32->bf16 convert helper ----------------
__device__ inline void conv_tile(float (*tile)[33], const float* __restrict__ src, int srcN,
                                 int k0, int sn0, unsigned short* __restrict__ dst, int dstK,
                                 int dn0) {
    int t = threadIdx.x;
    int r = t >> 3, c4 = (t & 7) * 4;
    float4 v = *(const float4*)&src[(size_t)(k0 + r) * srcN + sn0 + c4];
    tile[r][c4 + 0] = v.x;
    tile[r][c4 + 1] = v.y;
    tile[r][c4 + 2] = v.z;
    tile[r][c4 + 3] = v.w;
    __syncthreads();
    ushort4 o;
    o.x = f2bf(tile[c4 + 0][r]);
    o.y = f2bf(tile[c4 + 1][r]);
    o.z = f2bf(tile[c4 + 2][r]);
    o.w = f2bf(tile[c4 + 3][r]);
    *(ushort4*)&dst[(size_t)(dn0 + r) * dstK + k0 + c4] = o;
}

// ---------------- per-layer weight conversion: fp32 KxN -> bf16 NxK ----------------
__global__ __launch_bounds__(256) void convw_k(const float* __restrict__ wq,
                                               const float* __restrict__ wk,
                                               const float* __restrict__ wv,
                                               const float* __restrict__ wo,
                                               const float* __restrict__ w1,
                                               const float* __restrict__ w2,
                                               const float* __restrict__ bq,
                                               const float* __restrict__ bk,
                                               const float* __restrict__ bv,
                                               unsigned short* __restrict__ WQKV,
                                               unsigned short* __restrict__ WO16,
                                               unsigned short* __restrict__ W1T,
                                               unsigned short* __restrict__ W2T,
                                               float* __restrict__ BQKV, int l) {
    __shared__ float tile[32][33];
    int t = blockIdx.x;
    if (t == 0) {
        for (int i = threadIdx.x; i < 1536; i += 256)
            BQKV[i] = i < 512 ? bq[l * 512 + i]
                              : (i < 1024 ? bk[l * 512 + i - 512] : bv[l * 512 + i - 1024]);
    }
    if (t < 768) {
        int tn = t % 48, tk = t / 48;
        int n0 = tn * 32, k0 = tk * 32;
        const float* src;
        int sn0;
        if (n0 < 512) { src = wq + (size_t)l * 262144; sn0 = n0; }
        else if (n0 < 1024) { src = wk + (size_t)l * 262144; sn0 = n0 - 512; }
        else { src = wv + (size_t)l * 262144; sn0 = n0 - 1024; }
        conv_tile(tile, src, 512, k0, sn0, WQKV, 512, n0);
    } else if (t < 1024) {
        int tt = t - 768;
        int n0 = (tt % 16) * 32, k0 = (tt / 16) * 32;
        conv_tile(tile, wo + (size_t)l * 262144, 512, k0, n0, WO16, 512, n0);
    } else if (t < 2048) {
        int tt = t - 1024;
        int n0 = (tt % 64) * 32, k0 = (tt / 64) * 32;
        conv_tile(tile, w1 + (size_t)l * 1048576, 2048, k0, n0, W1T, 512, n0);
    } else {
        int tt = t - 2048;
        int n0 = (tt % 16) * 32, k0 = (tt / 16) * 32;
        conv_tile(tile, w2 + (size_t)l * 1048576, 512, k0, n0, W2T, 2048, n0);
    }
}

__global__ __launch_bounds__(256) void convout_k(const float* __restrict__ w_out,
                                                 unsigned short* __restrict__ WOUT16) {
    __shared__ float tile[32][33];
    int t = blockIdx.x;
    int n0 = (t % 32) * 32, k0 = (t / 32) * 32;
    conv_tile(tile, w_out, 1024, k0, n0, WOUT16, 512, n0);
}

// ---------------- bf16 MFMA GEMM: C = A(MxK,bf16) @ BT^T(NxK,bf16) + bias ----------------
// flags: 1 = relu, 2 = add into fp32 C, 4 = bf16 output
template <int BM, int BN>
__global__ __launch_bounds__(256) void gemm16_k(const unsigned short* __restrict__ A,
                                                const unsigned short* __restrict__ BT,
                                                const float* __restrict__ bias,
                                                void* __restrict__ Cp, int M, int N, int K,
                                                int flags) {
    constexpr int BK = 32, LDW = BK + 8;
    __shared__ unsigned short As[BM][LDW];
    __shared__ unsigned short Bs[BN][LDW];
    constexpr int TM = BM / 32, TN = BN / 32;
    int tid = threadIdx.x;
    int wave = tid >> 6, lane = tid & 63;
    int wm = wave >> 1, wn = wave & 1;
    int quad = lane >> 4, sub = lane & 15;
    int m0 = blockIdx.y * BM, n0 = blockIdx.x * BN;
    f32x4 acc[TM][TN] = {};
    for (int k0 = 0; k0 < K; k0 += BK) {
#pragma unroll
        for (int rep = 0; rep < (BM * 4) / 256; ++rep) {
            int ch = rep * 256 + tid;
            int row = ch >> 2, cw = ch & 3;
            int gr = m0 + row;
            int4 v = make_int4(0, 0, 0, 0);
            if (gr < M) v = *(const int4*)&A[(size_t)gr * K + k0 + cw * 8];
            *(int4*)&As[row][cw * 8] = v;
        }
#pragma unroll
        for (int rep = 0; rep < (BN * 4) / 256; ++rep) {
            int ch = rep * 256 + tid;
            int row = ch >> 2, cw = ch & 3;
            *(int4*)&Bs[row][cw * 8] = *(const int4*)&BT[(size_t)(n0 + row) * K + k0 + cw * 8];
        }
        __syncthreads();
        bf16x8 af[TM], bfr[TN];
#pragma unroll
        for (int mi = 0; mi < TM; ++mi)
            af[mi] = *(const bf16x8*)&As[wm * (BM / 2) + mi * 16 + sub][quad * 8];
#pragma unroll
        for (int ni = 0; ni < TN; ++ni)
            bfr[ni] = *(const bf16x8*)&Bs[wn * (BN / 2) + ni * 16 + sub][quad * 8];
#pragma unroll
        for (int mi = 0; mi < TM; ++mi)
#pragma unroll
            for (int ni = 0; ni < TN; ++ni)
                acc[mi][ni] =
                    __builtin_amdgcn_mfma_f32_16x16x32_bf16(af[mi], bfr[ni], acc[mi][ni], 0, 0, 0);
        __syncthreads();
    }
    bool relu = flags & 1, addc = flags & 2, obf = flags & 4;
    float* Cf = (float*)Cp;
    unsigned short* Ch = (unsigned short*)Cp;
#pragma unroll
    for (int mi = 0; mi < TM; ++mi) {
#pragma unroll
        for (int ni = 0; ni < TN; ++ni) {
#pragma unroll
            for (int r = 0; r < 4; ++r) {
                int row = m0 + wm * (BM / 2) + mi * 16 + quad * 4 + r;
                int col = n0 + wn * (BN / 2) + ni * 16 + sub;
                if (row < M) {
                    float v = acc[mi][ni][r] + bias[col];
                    if (relu) v = fmaxf(v, 0.f);
                    size_t idx = (size_t)row * N + col;
                    if (obf) {
                        Ch[idx] = f2bf(v);
                    } else {
                        if (addc) v += Cf[idx];
                        Cf[idx] = v;
                    }
                }
            }
        }
    }
}

// ---------------- attention on fused bf16 QKV buffer ----------------
__global__ __launch_bounds__(64) void attn_k(const unsigned short* __restrict__ QKV,
                                             unsigned short* __restrict__ ATT,
                                             const int* __restrict__ lrw) {
    int lane = threadIdx.x;
    int qrow = blockIdx.x;
    int bh = blockIdx.y;
    int b = bh >> 3, h = bh & 7;

    int i, is_sum;
    if (qrow < RT) {
        i = qrow >> 2;
        is_sum = 0;
    } else if (qrow < RT + UU) {
        i = (qrow - RT) >> 4;
        is_sum = 0;
    } else {
        i = qrow - (RT + UU);
        is_sum = 1;
    }
    int ms = (i > 4) ? (i - 4) : 0;
    int n_mem = is_sum ? 0 : (i - ms);
    int us = (i * 16 - 32 > 0) ? (i * 16 - 32) : 0;
    int ue = (i + 1) * 16;
    int total = n_mem + 4 + (ue - us);
    int klen = KN + lrw[b] - lrw[NB];

    __shared__ float qs[64];
    __shared__ float ps[64];
    __shared__ int kks[64];
    qs[lane] = bf2f(QKV[(size_t)(120 + qrow * NB + b) * 1536 + h * DH + lane]) * QSCALE;
    __syncthreads();

    int kk = -1;
    if (lane < total) {
        if (lane < n_mem)
            kk = ms + lane;
        else if (lane < n_mem + 4)
            kk = 15 + i * 4 + (lane - n_mem);
        else
            kk = 79 + us + (lane - n_mem - 4);
    }
    float s = NEGV;
    if (kk >= 0 && kk < klen) {
        const int4* kr = (const int4*)&QKV[(size_t)(kk * NB + b) * 1536 + 512 + h * DH];
        float accd = 0.f;
#pragma unroll
        for (int c = 0; c < 8; ++c) {
            int4 kv = kr[c];
            const int uu[4] = {kv.x, kv.y, kv.z, kv.w};
#pragma unroll
            for (int j = 0; j < 4; ++j) {
                float lo = __uint_as_float(((unsigned)uu[j]) << 16);
                float hi = __uint_as_float(((unsigned)uu[j]) & 0xFFFF0000u);
                accd = fmaf(lo, qs[c * 8 + j * 2], accd);
                accd = fmaf(hi, qs[c * 8 + j * 2 + 1], accd);
            }
        }
        s = accd;
    }
    float m = s;
#pragma unroll
    for (int off = 32; off; off >>= 1) m = fmaxf(m, __shfl_xor(m, off));
    float p = __expf(s - m);
    float sum = p;
#pragma unroll
    for (int off = 32; off; off >>= 1) sum += __shfl_xor(sum, off);
    float inv = 1.f / sum;
    ps[lane] = p * inv;
    kks[lane] = kk;
    __syncthreads();

    float acc = 0.f;
    for (int j = 0; j < total; ++j) {
        int kkj = kks[j];
        acc = fmaf(ps[j], bf2f(QKV[(size_t)(kkj * NB + b) * 1536 + 1024 + h * DH + lane]), acc);
    }
    ATT[(size_t)(qrow * NB + b) * D + h * DH + lane] = f2bf(acc);
}

// ---------------- residual add + new mems = tanh(summary out) ----------------
__global__ __launch_bounds__(256) void fuse_k(const float* __restrict__ OUTB,
                                              float* __restrict__ S,
                                              unsigned short* __restrict__ MEMS) {
    int idx = blockIdx.x * 256 + threadIdx.x;
    const int total1 = SROWS * NB * D;
    const int total2 = 15 * NB * D;
    if (idx < total1) {
        S[idx] += OUTB[idx];
    } else if (idx < total1 + total2) {
        int j = idx - total1;
        MEMS[j] = f2bf(tanhf(OUTB[total1 + j]));
    }
}

// ---------------- final LN (width 1024) with permuted output ----------------
__global__ __launch_bounds__(256) void final_ln_k(const float* __restrict__ Yb,
                                                  const float* __restrict__ g,
                                                  const float* __restrict__ be,
                                                  float* __restrict__ out) {
    int row = blockIdx.x;
    int u = row >> 3, b = row & 7;
    const float* x = Yb + (size_t)row * OUTD;
    float v[4];
    float s = 0.f, ss = 0.f;
#pragma unroll
    for (int j = 0; j < 4; ++j) {
        v[j] = x[threadIdx.x + j * 256];
        s += v[j];
        ss = fmaf(v[j], v[j], ss);
    }
#pragma unroll
    for (int off = 32; off; off >>= 1) {
        s += __shfl_xor(s, off);
        ss += __shfl_xor(ss, off);
    }
    __shared__ float rs_[4], rss_[4];
    int w = threadIdx.x >> 6;
    if ((threadIdx.x & 63) == 0) {
        rs_[w] = s;
        rss_[w] = ss;
    }
    __syncthreads();
    s = rs_[0] + rs_[1] + rs_[2] + rs_[3];
    ss = rss_[0] + rss_[1] + rss_[2] + rss_[3];
    float mean = s * (1.f / OUTD);
    float var = ss * (1.f / OUTD) - mean * mean;
    float rstd = rsqrtf(var + 1e-5f);
    float* o = out + ((size_t)(b * 256 + u)) * OUTD;
#pragma unroll
    for (int j = 0; j < 4; ++j) {
        int col = threadIdx.x + j * 256;
        o[col] = (v[j] - mean) * rstd * g[col] + be[col];
    }
}

extern "C" void kernel_launch(void* const* d_in, const int* in_sizes, int n_in, void* d_out,
                              int out_size, void* d_ws, size_t ws_size, hipStream_t stream) {
    (void)in_sizes;
    (void)n_in;
    (void)out_size;
    (void)ws_size;
    const float* input = (const float*)d_in[0];
    const int* lengths = (const int*)d_in[1];
    const float* w_in = (const float*)d_in[2];
    const float* ln_in_g = (const float*)d_in[3];
    const float* ln_in_b = (const float*)d_in[4];
    const float* wq = (const float*)d_in[5];
    const float* bq = (const float*)d_in[6];
    const float* wk = (const float*)d_in[7];
    const float* bk = (const float*)d_in[8];
    const float* wv = (const float*)d_in[9];
    const float* bv = (const float*)d_in[10];
    const float* wo = (const float*)d_in[11];
    const float* bo = (const float*)d_in[12];
    const float* ff_g = (const float*)d_in[13];
    const float* ff_b = (const float*)d_in[14];
    const float* w1 = (const float*)d_in[15];
    const float* b1 = (const float*)d_in[16];
    const float* w2 = (const float*)d_in[17];
    const float* b2 = (const float*)d_in[18];
    const float* lo_g = (const float*)d_in[19];
    const float* lo_b = (const float*)d_in[20];
    const float* w_out = (const float*)d_in[21];
    const float* b_out = (const float*)d_in[22];
    const float* lng = (const float*)d_in[23];
    const float* lnb = (const float*)d_in[24];
    float* out = (float*)d_out;

    char* wsc = (char*)d_ws;
    size_t off = 0;
    auto alloc = [&](size_t bytes) {
        char* p = wsc + off;
        off += (bytes + 255) & ~(size_t)255;
        return p;
    };
    unsigned short* ACT16 = (unsigned short*)alloc(2808ULL * 512 * 2);
    unsigned short* ATT16 = (unsigned short*)alloc(2688ULL * 512 * 2);
    unsigned short* HB16 = (unsigned short*)alloc(2560ULL * 2048 * 2);
    unsigned short* QKVB = (unsigned short*)alloc(2808ULL * 1536 * 2);
    float* SB = (float*)alloc(2560ULL * 512 * 4);
    unsigned short* WQKV16 = (unsigned short*)alloc(1536ULL * 512 * 2);
    unsigned short* WO16 = (unsigned short*)alloc(512ULL * 512 * 2);
    unsigned short* W1T = (unsigned short*)alloc(2048ULL * 512 * 2);
    unsigned short* W2T = (unsigned short*)alloc(512ULL * 2048 * 2);
    unsigned short* WOUT16 = (unsigned short*)alloc(1024ULL * 512 * 2);
    float* BQKV = (float*)alloc(1536 * 4);
    int* LRW = (int*)alloc(64);

    unsigned short* MEMS16 = ACT16;                 // 120 rows
    unsigned short* LNB16 = ACT16 + 120 * 512;      // 2560 rows
    unsigned short* SUMB16 = ACT16 + 2680 * 512;    // 128 rows
    float* XB = (float*)QKVB;    // init-time alias
    float* OUTB = (float*)QKVB;  // post-attention alias
    float* HBf = (float*)QKVB;   // final-proj alias

    lr_k<<<1, 64, 0, stream>>>(lengths, LRW, out + (size_t)NB * 256 * 1024);
    convout_k<<<512, 256, 0, stream>>>(w_out, WOUT16);
    inproj_k<<<TR * NB, 128, 0, stream>>>(input, w_in, XB);
    initstate_k<<<SROWS * NB, 256, 0, stream>>>(XB, SB);
    mems0_k<<<15 * NB, 256, 0, stream>>>(XB, MEMS16);

    for (int l = 0; l < LAYERS; ++l) {
        convw_k<<<3072, 256, 0, stream>>>(wq, wk, wv, wo, w1, w2, bq, bk, bv, WQKV16, WO16, W1T,
                                          W2T, BQKV, l);
        ln_k<<<SROWS * NB, 256, 0, stream>>>(SB, LNB16, SB, ln_in_g + l * D, ln_in_b + l * D, 0);
        summary_k<<<NSEG * NB, 256, 0, stream>>>(LNB16, SUMB16);
        // fused QKV: A = [MEMS][LN][SUM] (2808 rows), N = 1536
        gemm16_k<128, 128><<<dim3(12, 22), 256, 0, stream>>>(ACT16, WQKV16, BQKV, QKVB, 2808,
                                                             1536, 512, 4);
        attn_k<<<dim3(QN, NB * H), 64, 0, stream>>>(QKVB, ATT16, LRW);
        gemm16_k<128, 64><<<dim3(8, 21), 256, 0, stream>>>(ATT16, WO16, bo + l * D, OUTB,
                                                           QN * NB, D, D, 0);
        fuse_k<<<(SROWS * NB * D + 15 * NB * D) / 256, 256, 0, stream>>>(OUTB, SB, MEMS16);
        ln_k<<<SROWS * NB, 256, 0, stream>>>(SB, LNB16, SB, ff_g + l * D, ff_b + l * D, 0);
        gemm16_k<128, 128><<<dim3(16, 20), 256, 0, stream>>>(LNB16, W1T, b1 + l * FFN_D, HB16,
                                                             SROWS * NB, FFN_D, D, 1 | 4);
        gemm16_k<128, 64><<<dim3(8, 20), 256, 0, stream>>>(HB16, W2T, b2 + l * D, SB, SROWS * NB,
                                                           D, FFN_D, 2);
        ln_k<<<SROWS * NB, 256, 0, stream>>>(SB, LNB16, SB, lo_g + l * D, lo_b + l * D, 1);
    }
    // final projection of utt rows (LNB16 rows 64*NB ..) then LN -> out
    gemm16_k<128, 128><<<dim3(8, 16), 256, 0, stream>>>(LNB16 + (size_t)RT * NB * D, WOUT16,
                                                        b_out, HBf, UU * NB, OUTD, D, 0);
    final_ln_k<<<UU * NB, 256, 0, stream>>>(HBf, lng, lnb, out);
}

// Round 3
// 1276.165 us; speedup vs baseline: 3.6960x; 1.4113x over previous
//
#include <hip/hip_runtime.h>
#include <math.h>

#define NB 8
#define D 512
#define H 8
#define DH 64
#define NSEG 16
#define RT 64
#define UU 256
#define QN 336
#define KN 335
#define SROWS 320
#define FFN_D 2048
#define LAYERS 8
#define OUTD 1024
#define TR 260
#define NEGV (-100000000.0f)
#define QSCALE 0.125f

typedef __attribute__((ext_vector_type(8))) short bf16x8;
typedef __attribute__((ext_vector_type(4))) float f32x4;

__device__ inline unsigned short f2bf(float f) {
    union { float f; unsigned int u; } v; v.f = f;
    unsigned int u = v.u;
    unsigned int r = (u + 0x7FFFu + ((u >> 16) & 1u)) >> 16;
    return (unsigned short)r;
}
__device__ inline float bf2f(unsigned short h) {
    union { unsigned int u; float f; } v; v.u = ((unsigned int)h) << 16;
    return v.f;
}

// ---------------- lr + max ----------------
__global__ void lr_k(const int* __restrict__ lengths, int* __restrict__ lrw,
                     float* __restrict__ out_lr) {
    if (threadIdx.x == 0) {
        int mx = 0;
        for (int b = 0; b < NB; ++b) {
            int v = lengths[b] >> 2;
            lrw[b] = v;
            out_lr[b] = (float)v;
            if (v > mx) mx = v;
        }
        lrw[NB] = mx;
    }
}

// ---------------- input projection + reshape to (t,b,512) ----------------
__global__ __launch_bounds__(128) void inproj_k(const float* __restrict__ input,
                                                const float* __restrict__ w_in,
                                                float* __restrict__ XB) {
    __shared__ float wl[80 * 128];
    __shared__ float il[4 * 80];
    int tid = threadIdx.x;
    int t = blockIdx.x >> 3;
    int b = blockIdx.x & 7;
    for (int i = tid; i < 80 * 128; i += 128) wl[i] = w_in[i];
    const float* inp = input + ((size_t)b * 1040 + (size_t)t * 4) * 80;
    for (int i = tid; i < 320; i += 128) il[i] = inp[i];
    __syncthreads();
    float* xrow = XB + ((size_t)(t * NB + b)) * D;
#pragma unroll
    for (int c = 0; c < 4; ++c) {
        float acc = 0.f;
        for (int i = 0; i < 80; ++i) acc = fmaf(il[c * 80 + i], wl[i * 128 + tid], acc);
        xrow[c * 128 + tid] = acc;
    }
}

// ---------------- init state S = [rc(64), utt(256)] (fp32) ----------------
__global__ __launch_bounds__(256) void initstate_k(const float* __restrict__ XB,
                                                   float* __restrict__ S) {
    int r = blockIdx.x;
    int srow = r >> 3, b = r & 7;
    int src;
    if (srow < RT) {
        int i = srow >> 2, jj = srow & 3;
        src = (i < 15 ? (i + 1) * 16 : 256) + jj;
    } else {
        src = srow - RT;
    }
    const float* xr = XB + ((size_t)(src * NB + b)) * D;
    float* sr = S + (size_t)r * D;
    sr[threadIdx.x] = xr[threadIdx.x];
    sr[threadIdx.x + 256] = xr[threadIdx.x + 256];
}

// ---------------- initial mems -> bf16 ----------------
__global__ __launch_bounds__(256) void mems0_k(const float* __restrict__ XB,
                                               unsigned short* __restrict__ MEMS) {
    int ib = blockIdx.x;
    int i = ib >> 3, b = ib & 7;
    for (int c = 0; c < 2; ++c) {
        int col = threadIdx.x + c * 256;
        float s = 0.f;
#pragma unroll
        for (int t = 0; t < 16; ++t) s += XB[((size_t)((i * 16 + t) * NB + b)) * D + col];
        MEMS[(size_t)ib * D + col] = f2bf(s * (1.f / 16.f));
    }
}

// ---------------- LayerNorm: fp32 in, bf16 out (+optional fp32 out) ----------------
__global__ __launch_bounds__(256) void ln_k(const float* __restrict__ X,
                                            unsigned short* __restrict__ Y16,
                                            float* __restrict__ Yf,
                                            const float* __restrict__ g,
                                            const float* __restrict__ be, int dual) {
    int row = blockIdx.x;
    const float* x = X + (size_t)row * D;
    float v[2];
    float s = 0.f, ss = 0.f;
#pragma unroll
    for (int j = 0; j < 2; ++j) {
        v[j] = x[threadIdx.x + j * 256];
        s += v[j];
        ss = fmaf(v[j], v[j], ss);
    }
#pragma unroll
    for (int off = 32; off; off >>= 1) {
        s += __shfl_xor(s, off);
        ss += __shfl_xor(ss, off);
    }
    __shared__ float rs_[4], rss_[4];
    int w = threadIdx.x >> 6;
    if ((threadIdx.x & 63) == 0) {
        rs_[w] = s;
        rss_[w] = ss;
    }
    __syncthreads();
    s = rs_[0] + rs_[1] + rs_[2] + rs_[3];
    ss = rss_[0] + rss_[1] + rss_[2] + rss_[3];
    float mean = s * (1.f / D);
    float var = ss * (1.f / D) - mean * mean;
    float rstd = rsqrtf(var + 1e-5f);
#pragma unroll
    for (int j = 0; j < 2; ++j) {
        int col = threadIdx.x + j * 256;
        float y = (v[j] - mean) * rstd * g[col] + be[col];
        Y16[(size_t)row * D + col] = f2bf(y);
        if (dual) Yf[(size_t)row * D + col] = y;
    }
}

// ---------------- residual add + LN + mems-tanh fused ----------------
__global__ __launch_bounds__(256) void ln_res_k(const float* __restrict__ OUTB,
                                                float* __restrict__ SB,
                                                unsigned short* __restrict__ MEMS,
                                                unsigned short* __restrict__ Y16,
                                                const float* __restrict__ g,
                                                const float* __restrict__ be) {
    int row = blockIdx.x;
    if (row >= SROWS * NB) {
        int j = row - SROWS * NB;
#pragma unroll
        for (int c = 0; c < 2; ++c) {
            int col = threadIdx.x + c * 256;
            MEMS[(size_t)j * D + col] = f2bf(tanhf(OUTB[(size_t)row * D + col]));
        }
        return;
    }
    float v[2];
    float s = 0.f, ss = 0.f;
#pragma unroll
    for (int j = 0; j < 2; ++j) {
        int col = threadIdx.x + j * 256;
        float r = SB[(size_t)row * D + col] + OUTB[(size_t)row * D + col];
        SB[(size_t)row * D + col] = r;
        v[j] = r;
        s += r;
        ss = fmaf(r, r, ss);
    }
#pragma unroll
    for (int off = 32; off; off >>= 1) {
        s += __shfl_xor(s, off);
        ss += __shfl_xor(ss, off);
    }
    __shared__ float rs_[4], rss_[4];
    int w = threadIdx.x >> 6;
    if ((threadIdx.x & 63) == 0) {
        rs_[w] = s;
        rss_[w] = ss;
    }
    __syncthreads();
    s = rs_[0] + rs_[1] + rs_[2] + rs_[3];
    ss = rss_[0] + rss_[1] + rss_[2] + rss_[3];
    float mean = s * (1.f / D);
    float var = ss * (1.f / D) - mean * mean;
    float rstd = rsqrtf(var + 1e-5f);
#pragma unroll
    for (int j = 0; j < 2; ++j) {
        int col = threadIdx.x + j * 256;
        Y16[(size_t)row * D + col] = f2bf((v[j] - mean) * rstd * g[col] + be[col]);
    }
}

// ---------------- summary = per-segment mean of ln_utt (bf16) ----------------
__global__ __launch_bounds__(256) void summary_k(const unsigned short* __restrict__ LN16,
                                                 unsigned short* __restrict__ SUM16) {
    int ib = blockIdx.x;
    int i = ib >> 3, b = ib & 7;
    for (int c = 0; c < 2; ++c) {
        int col = threadIdx.x + c * 256;
        float s = 0.f;
#pragma unroll
        for (int t = 0; t < 16; ++t)
            s += bf2f(LN16[((size_t)((RT + i * 16 + t) * NB + b)) * D + col]);
        SUM16[(size_t)ib * D + col] = f2bf(s * (1.f / 16.f));
    }
}

// ---------------- 32x32 transpose + fp32->bf16 convert helper ----------------
__device__ inline void conv_tile(float (*tile)[33], const float* __restrict__ src, int srcN,
                                 int k0, int sn0, unsigned short* __restrict__ dst, int dstK,
                                 int dn0) {
    int t = threadIdx.x;
    int r = t >> 3, c4 = (t & 7) * 4;
    float4 v = *(const float4*)&src[(size_t)(k0 + r) * srcN + sn0 + c4];
    tile[r][c4 + 0] = v.x;
    tile[r][c4 + 1] = v.y;
    tile[r][c4 + 2] = v.z;
    tile[r][c4 + 3] = v.w;
    __syncthreads();
    ushort4 o;
    o.x = f2bf(tile[c4 + 0][r]);
    o.y = f2bf(tile[c4 + 1][r]);
    o.z = f2bf(tile[c4 + 2][r]);
    o.w = f2bf(tile[c4 + 3][r]);
    *(ushort4*)&dst[(size_t)(dn0 + r) * dstK + k0 + c4] = o;
}

// ---------------- per-layer weight conversion: fp32 KxN -> bf16 NxK ----------------
__global__ __launch_bounds__(256) void convw_k(const float* __restrict__ wq,
                                               const float* __restrict__ wk,
                                               const float* __restrict__ wv,
                                               const float* __restrict__ wo,
                                               const float* __restrict__ w1,
                                               const float* __restrict__ w2,
                                               const float* __restrict__ bq,
                                               const float* __restrict__ bk,
                                               const float* __restrict__ bv,
                                               unsigned short* __restrict__ WQKV,
                                               unsigned short* __restrict__ WO16,
                                               unsigned short* __restrict__ W1T,
                                               unsigned short* __restrict__ W2T,
                                               float* __restrict__ BQKV, int l) {
    __shared__ float tile[32][33];
    int t = blockIdx.x;
    if (t == 0) {
        for (int i = threadIdx.x; i < 1536; i += 256)
            BQKV[i] = i < 512 ? bq[l * 512 + i]
                              : (i < 1024 ? bk[l * 512 + i - 512] : bv[l * 512 + i - 1024]);
    }
    if (t < 768) {
        int tn = t % 48, tk = t / 48;
        int n0 = tn * 32, k0 = tk * 32;
        const float* src;
        int sn0;
        if (n0 < 512) { src = wq + (size_t)l * 262144; sn0 = n0; }
        else if (n0 < 1024) { src = wk + (size_t)l * 262144; sn0 = n0 - 512; }
        else { src = wv + (size_t)l * 262144; sn0 = n0 - 1024; }
        conv_tile(tile, src, 512, k0, sn0, WQKV, 512, n0);
    } else if (t < 1024) {
        int tt = t - 768;
        int n0 = (tt % 16) * 32, k0 = (tt / 16) * 32;
        conv_tile(tile, wo + (size_t)l * 262144, 512, k0, n0, WO16, 512, n0);
    } else if (t < 2048) {
        int tt = t - 1024;
        int n0 = (tt % 64) * 32, k0 = (tt / 64) * 32;
        conv_tile(tile, w1 + (size_t)l * 1048576, 2048, k0, n0, W1T, 512, n0);
    } else {
        int tt = t - 2048;
        int n0 = (tt % 16) * 32, k0 = (tt / 16) * 32;
        conv_tile(tile, w2 + (size_t)l * 1048576, 512, k0, n0, W2T, 2048, n0);
    }
}

__global__ __launch_bounds__(256) void convout_k(const float* __restrict__ w_out,
                                                 unsigned short* __restrict__ WOUT16) {
    __shared__ float tile[32][33];
    int t = blockIdx.x;
    int n0 = (t % 32) * 32, k0 = (t / 32) * 32;
    conv_tile(tile, w_out, 1024, k0, n0, WOUT16, 512, n0);
}

// ---------------- bf16 MFMA GEMM, 64x64 tile, BK=64, register double-buffer ----------
// flags: 1 = relu, 2 = add into fp32 C, 4 = bf16 output, 8 = atomicAdd into fp32 C
__global__ __launch_bounds__(256) void gemm16_k(const unsigned short* __restrict__ A,
                                                const unsigned short* __restrict__ BT,
                                                const float* __restrict__ bias,
                                                void* __restrict__ Cp, int M, int N, int K,
                                                int Kchunk, int flags) {
    __shared__ unsigned short As[2][64][40];
    __shared__ unsigned short Bs[2][64][40];
    int tid = threadIdx.x;
    int wave = tid >> 6, lane = tid & 63;
    int wm = wave >> 1, wn = wave & 1;
    int quad = lane >> 4, sub = lane & 15;
    int m0 = blockIdx.y * 64, n0 = blockIdx.x * 64;
    int kb = blockIdx.z * Kchunk, ke = kb + Kchunk;

    int lrow = tid >> 3, lkc = tid & 7;           // chunk 0: rows 0..31
    int lrow2 = lrow + 32;                        // chunk 1: rows 32..63
    int lkh = lkc >> 2, lkl = lkc & 3;

    f32x4 acc[2][2] = {};
    int4 ar0, ar1, br0, br1;

    auto loadT = [&](int k0) {
        int gr0 = m0 + lrow, gr1 = m0 + lrow2;
        ar0 = (gr0 < M) ? *(const int4*)&A[(size_t)gr0 * K + k0 + lkc * 8] : make_int4(0, 0, 0, 0);
        ar1 = (gr1 < M) ? *(const int4*)&A[(size_t)gr1 * K + k0 + lkc * 8] : make_int4(0, 0, 0, 0);
        br0 = *(const int4*)&BT[(size_t)(n0 + lrow) * K + k0 + lkc * 8];
        br1 = *(const int4*)&BT[(size_t)(n0 + lrow2) * K + k0 + lkc * 8];
    };
    auto storeT = [&]() {
        *(int4*)&As[lkh][lrow][lkl * 8] = ar0;
        *(int4*)&As[lkh][lrow2][lkl * 8] = ar1;
        *(int4*)&Bs[lkh][lrow][lkl * 8] = br0;
        *(int4*)&Bs[lkh][lrow2][lkl * 8] = br1;
    };
    auto compute = [&]() {
#pragma unroll
        for (int ks = 0; ks < 2; ++ks) {
            bf16x8 af[2], bf[2];
#pragma unroll
            for (int mi = 0; mi < 2; ++mi)
                af[mi] = *(const bf16x8*)&As[ks][wm * 32 + mi * 16 + sub][quad * 8];
#pragma unroll
            for (int ni = 0; ni < 2; ++ni)
                bf[ni] = *(const bf16x8*)&Bs[ks][wn * 32 + ni * 16 + sub][quad * 8];
#pragma unroll
            for (int mi = 0; mi < 2; ++mi)
#pragma unroll
                for (int ni = 0; ni < 2; ++ni)
                    acc[mi][ni] = __builtin_amdgcn_mfma_f32_16x16x32_bf16(af[mi], bf[ni],
                                                                          acc[mi][ni], 0, 0, 0);
        }
    };

    loadT(kb);
    storeT();
    __syncthreads();
    for (int k0 = kb + 64; k0 < ke; k0 += 64) {
        loadT(k0);
        compute();
        __syncthreads();
        storeT();
        __syncthreads();
    }
    compute();

    bool relu = flags & 1, addc = flags & 2, obf = flags & 4, atom = flags & 8;
    bool addbias = !atom || blockIdx.z == 0;
    float* Cf = (float*)Cp;
    unsigned short* Ch = (unsigned short*)Cp;
#pragma unroll
    for (int mi = 0; mi < 2; ++mi) {
#pragma unroll
        for (int ni = 0; ni < 2; ++ni) {
#pragma unroll
            for (int r = 0; r < 4; ++r) {
                int row = m0 + wm * 32 + mi * 16 + quad * 4 + r;
                int col = n0 + wn * 32 + ni * 16 + sub;
                if (row < M) {
                    float v = acc[mi][ni][r] + (addbias ? bias[col] : 0.f);
                    if (relu) v = fmaxf(v, 0.f);
                    size_t idx = (size_t)row * N + col;
                    if (obf) {
                        Ch[idx] = f2bf(v);
                    } else if (atom) {
                        atomicAdd(&Cf[idx], v);
                    } else {
                        if (addc) v += Cf[idx];
                        Cf[idx] = v;
                    }
                }
            }
        }
    }
}

// ---------------- attention on fused bf16 QKV buffer ----------------
__global__ __launch_bounds__(64) void attn_k(const unsigned short* __restrict__ QKV,
                                             unsigned short* __restrict__ ATT,
                                             const int* __restrict__ lrw) {
    int lane = threadIdx.x;
    int qrow = blockIdx.x;
    int bh = blockIdx.y;
    int b = bh >> 3, h = bh & 7;

    int i, is_sum;
    if (qrow < RT) {
        i = qrow >> 2;
        is_sum = 0;
    } else if (qrow < RT + UU) {
        i = (qrow - RT) >> 4;
        is_sum = 0;
    } else {
        i = qrow - (RT + UU);
        is_sum = 1;
    }
    int ms = (i > 4) ? (i - 4) : 0;
    int n_mem = is_sum ? 0 : (i - ms);
    int us = (i * 16 - 32 > 0) ? (i * 16 - 32) : 0;
    int ue = (i + 1) * 16;
    int total = n_mem + 4 + (ue - us);
    int klen = KN + lrw[b] - lrw[NB];

    __shared__ float qs[64];
    __shared__ float ps[64];
    __shared__ int kks[64];
    qs[lane] = bf2f(QKV[(size_t)(120 + qrow * NB + b) * 1536 + h * DH + lane]) * QSCALE;
    __syncthreads();

    int kk = -1;
    if (lane < total) {
        if (lane < n_mem)
            kk = ms + lane;
        else if (lane < n_mem + 4)
            kk = 15 + i * 4 + (lane - n_mem);
        else
            kk = 79 + us + (lane - n_mem - 4);
    }
    float s = NEGV;
    if (kk >= 0 && kk < klen) {
        const int4* kr = (const int4*)&QKV[(size_t)(kk * NB + b) * 1536 + 512 + h * DH];
        float accd = 0.f;
#pragma unroll
        for (int c = 0; c < 8; ++c) {
            int4 kv = kr[c];
            const int uu[4] = {kv.x, kv.y, kv.z, kv.w};
#pragma unroll
            for (int j = 0; j < 4; ++j) {
                float lo = __uint_as_float(((unsigned)uu[j]) << 16);
                float hi = __uint_as_float(((unsigned)uu[j]) & 0xFFFF0000u);
                accd = fmaf(lo, qs[c * 8 + j * 2], accd);
                accd = fmaf(hi, qs[c * 8 + j * 2 + 1], accd);
            }
        }
        s = accd;
    }
    float m = s;
#pragma unroll
    for (int off = 32; off; off >>= 1) m = fmaxf(m, __shfl_xor(m, off));
    float p = __expf(s - m);
    float sum = p;
#pragma unroll
    for (int off = 32; off; off >>= 1) sum += __shfl_xor(sum, off);
    float inv = 1.f / sum;
    ps[lane] = p * inv;
    kks[lane] = kk;
    __syncthreads();

    float acc = 0.f;
    for (int j = 0; j < total; ++j) {
        int kkj = kks[j];
        acc = fmaf(ps[j], bf2f(QKV[(size_t)(kkj * NB + b) * 1536 + 1024 + h * DH + lane]), acc);
    }
    ATT[(size_t)(qrow * NB + b) * D + h * DH + lane] = f2bf(acc);
}

// ---------------- final LN (width 1024) with permuted output ----------------
__global__ __launch_bounds__(256) void final_ln_k(const float* __restrict__ Yb,
                                                  const float* __restrict__ g,
                                                  const float* __restrict__ be,
                                                  float* __restrict__ out) {
    int row = blockIdx.x;
    int u = row >> 3, b = row & 7;
    const float* x = Yb + (size_t)row * OUTD;
    float v[4];
    float s = 0.f, ss = 0.f;
#pragma unroll
    for (int j = 0; j < 4; ++j) {
        v[j] = x[threadIdx.x + j * 256];
        s += v[j];
        ss = fmaf(v[j], v[j], ss);
    }
#pragma unroll
    for (int off = 32; off; off >>= 1) {
        s += __shfl_xor(s, off);
        ss += __shfl_xor(ss, off);
    }
    __shared__ float rs_[4], rss_[4];
    int w = threadIdx.x >> 6;
    if ((threadIdx.x & 63) == 0) {
        rs_[w] = s;
        rss_[w] = ss;
    }
    __syncthreads();
    s = rs_[0] + rs_[1] + rs_[2] + rs_[3];
    ss = rss_[0] + rss_[1] + rss_[2] + rss_[3];
    float mean = s * (1.f / OUTD);
    float var = ss * (1.f / OUTD) - mean * mean;
    float rstd = rsqrtf(var + 1e-5f);
    float* o = out + ((size_t)(b * 256 + u)) * OUTD;
#pragma unroll
    for (int j = 0; j < 4; ++j) {
        int col = threadIdx.x + j * 256;
        o[col] = (v[j] - mean) * rstd * g[col] + be[col];
    }
}

extern "C" void kernel_launch(void* const* d_in, const int* in_sizes, int n_in, void* d_out,
                              int out_size, void* d_ws, size_t ws_size, hipStream_t stream) {
    (void)in_sizes;
    (void)n_in;
    (void)out_size;
    (void)ws_size;
    const float* input = (const float*)d_in[0];
    const int* lengths = (const int*)d_in[1];
    const float* w_in = (const float*)d_in[2];
    const float* ln_in_g = (const float*)d_in[3];
    const float* ln_in_b = (const float*)d_in[4];
    const float* wq = (const float*)d_in[5];
    const float* bq = (const float*)d_in[6];
    const float* wk = (const float*)d_in[7];
    const float* bk = (const float*)d_in[8];
    const float* wv = (const float*)d_in[9];
    const float* bv = (const float*)d_in[10];
    const float* wo = (const float*)d_in[11];
    const float* bo = (const float*)d_in[12];
    const float* ff_g = (const float*)d_in[13];
    const float* ff_b = (const float*)d_in[14];
    const float* w1 = (const float*)d_in[15];
    const float* b1 = (const float*)d_in[16];
    const float* w2 = (const float*)d_in[17];
    const float* b2 = (const float*)d_in[18];
    const float* lo_g = (const float*)d_in[19];
    const float* lo_b = (const float*)d_in[20];
    const float* w_out = (const float*)d_in[21];
    const float* b_out = (const float*)d_in[22];
    const float* lng = (const float*)d_in[23];
    const float* lnb = (const float*)d_in[24];
    float* out = (float*)d_out;

    char* wsc = (char*)d_ws;
    size_t off = 0;
    auto alloc = [&](size_t bytes) {
        char* p = wsc + off;
        off += (bytes + 255) & ~(size_t)255;
        return p;
    };
    unsigned short* ACT16 = (unsigned short*)alloc(2808ULL * 512 * 2);
    unsigned short* ATT16 = (unsigned short*)alloc(2688ULL * 512 * 2);
    unsigned short* HB16 = (unsigned short*)alloc(2560ULL * 2048 * 2);
    unsigned short* QKVB = (unsigned short*)alloc(2808ULL * 1536 * 2);
    float* SB = (float*)alloc(2560ULL * 512 * 4);
    unsigned short* WQKV16 = (unsigned short*)alloc(1536ULL * 512 * 2);
    unsigned short* WO16 = (unsigned short*)alloc(512ULL * 512 * 2);
    unsigned short* W1T = (unsigned short*)alloc(2048ULL * 512 * 2);
    unsigned short* W2T = (unsigned short*)alloc(512ULL * 2048 * 2);
    unsigned short* WOUT16 = (unsigned short*)alloc(1024ULL * 512 * 2);
    float* BQKV = (float*)alloc(1536 * 4);
    int* LRW = (int*)alloc(64);

    unsigned short* MEMS16 = ACT16;               // 120 rows
    unsigned short* LNB16 = ACT16 + 120 * 512;    // 2560 rows
    unsigned short* SUMB16 = ACT16 + 2680 * 512;  // 128 rows
    float* XB = (float*)QKVB;    // init-time alias
    float* OUTB = (float*)QKVB;  // post-attention alias
    float* HBf = (float*)QKVB;   // final-proj alias

    lr_k<<<1, 64, 0, stream>>>(lengths, LRW, out + (size_t)NB * 256 * 1024);
    convout_k<<<512, 256, 0, stream>>>(w_out, WOUT16);
    inproj_k<<<TR * NB, 128, 0, stream>>>(input, w_in, XB);
    initstate_k<<<SROWS * NB, 256, 0, stream>>>(XB, SB);
    mems0_k<<<15 * NB, 256, 0, stream>>>(XB, MEMS16);

    for (int l = 0; l < LAYERS; ++l) {
        convw_k<<<3072, 256, 0, stream>>>(wq, wk, wv, wo, w1, w2, bq, bk, bv, WQKV16, WO16, W1T,
                                          W2T, BQKV, l);
        ln_k<<<SROWS * NB, 256, 0, stream>>>(SB, LNB16, SB, ln_in_g + l * D, ln_in_b + l * D, 0);
        summary_k<<<NSEG * NB, 256, 0, stream>>>(LNB16, SUMB16);
        // fused QKV: A = [MEMS][LN][SUM] (2808 rows), N = 1536
        gemm16_k<<<dim3(24, 44, 1), 256, 0, stream>>>(ACT16, WQKV16, BQKV, QKVB, 2808, 1536, 512,
                                                      512, 4);
        attn_k<<<dim3(QN, NB * H), 64, 0, stream>>>(QKVB, ATT16, LRW);
        gemm16_k<<<dim3(8, 42, 1), 256, 0, stream>>>(ATT16, WO16, bo + l * D, OUTB, QN * NB, D,
                                                     D, D, 0);
        ln_res_k<<<(SROWS + 15) * NB, 256, 0, stream>>>(OUTB, SB, MEMS16, LNB16, ff_g + l * D,
                                                        ff_b + l * D);
        gemm16_k<<<dim3(32, 40, 1), 256, 0, stream>>>(LNB16, W1T, b1 + l * FFN_D, HB16,
                                                      SROWS * NB, FFN_D, D, D, 1 | 4);
        gemm16_k<<<dim3(8, 40, 4), 256, 0, stream>>>(HB16, W2T, b2 + l * D, SB, SROWS * NB, D,
                                                     FFN_D, 512, 8);
        ln_k<<<SROWS * NB, 256, 0, stream>>>(SB, LNB16, SB, lo_g + l * D, lo_b + l * D, 1);
    }
    // final projection of utt rows (LNB16 rows 64*NB ..) then LN -> out
    gemm16_k<<<dim3(16, 32, 1), 256, 0, stream>>>(LNB16 + (size_t)RT * NB * D, WOUT16, b_out,
                                                  HBf, UU * NB, OUTD, D, D, 0);
    final_ln_k<<<UU * NB, 256, 0, stream>>>(HBf, lng, lnb, out);
}

// Round 4
// 1195.788 us; speedup vs baseline: 3.9445x; 1.0672x over previous
//
#include <hip/hip_runtime.h>
#include <math.h>

#define NB 8
#define D 512
#define H 8
#define DH 64
#define NSEG 16
#define RT 64
#define UU 256
#define QN 336
#define KN 335
#define SROWS 320
#define FFN_D 2048
#define LAYERS 8
#define OUTD 1024
#define TR 260
#define NEGV (-100000000.0f)
#define QSCALE 0.125f

typedef __attribute__((ext_vector_type(8))) short bf16x8;
typedef __attribute__((ext_vector_type(4))) float f32x4;

__device__ inline unsigned short f2bf(float f) {
    union { float f; unsigned int u; } v; v.f = f;
    unsigned int u = v.u;
    unsigned int r = (u + 0x7FFFu + ((u >> 16) & 1u)) >> 16;
    return (unsigned short)r;
}
__device__ inline float bf2f(unsigned short h) {
    union { unsigned int u; float f; } v; v.u = ((unsigned int)h) << 16;
    return v.f;
}

// ---------------- lr + max ----------------
__global__ void lr_k(const int* __restrict__ lengths, int* __restrict__ lrw,
                     float* __restrict__ out_lr) {
    if (threadIdx.x == 0) {
        int mx = 0;
        for (int b = 0; b < NB; ++b) {
            int v = lengths[b] >> 2;
            lrw[b] = v;
            out_lr[b] = (float)v;
            if (v > mx) mx = v;
        }
        lrw[NB] = mx;
    }
}

// ---------------- input projection + reshape to (t,b,512) ----------------
__global__ __launch_bounds__(128) void inproj_k(const float* __restrict__ input,
                                                const float* __restrict__ w_in,
                                                float* __restrict__ XB) {
    __shared__ float wl[80 * 128];
    __shared__ float il[4 * 80];
    int tid = threadIdx.x;
    int t = blockIdx.x >> 3;
    int b = blockIdx.x & 7;
    for (int i = tid; i < 80 * 128; i += 128) wl[i] = w_in[i];
    const float* inp = input + ((size_t)b * 1040 + (size_t)t * 4) * 80;
    for (int i = tid; i < 320; i += 128) il[i] = inp[i];
    __syncthreads();
    float* xrow = XB + ((size_t)(t * NB + b)) * D;
#pragma unroll
    for (int c = 0; c < 4; ++c) {
        float acc = 0.f;
        for (int i = 0; i < 80; ++i) acc = fmaf(il[c * 80 + i], wl[i * 128 + tid], acc);
        xrow[c * 128 + tid] = acc;
    }
}

// ---------------- init state S = [rc(64), utt(256)] (fp32) ----------------
__global__ __launch_bounds__(256) void initstate_k(const float* __restrict__ XB,
                                                   float* __restrict__ S) {
    int r = blockIdx.x;
    int srow = r >> 3, b = r & 7;
    int src;
    if (srow < RT) {
        int i = srow >> 2, jj = srow & 3;
        src = (i < 15 ? (i + 1) * 16 : 256) + jj;
    } else {
        src = srow - RT;
    }
    const float* xr = XB + ((size_t)(src * NB + b)) * D;
    float* sr = S + (size_t)r * D;
    sr[threadIdx.x] = xr[threadIdx.x];
    sr[threadIdx.x + 256] = xr[threadIdx.x + 256];
}

// ---------------- initial mems -> bf16 ----------------
__global__ __launch_bounds__(256) void mems0_k(const float* __restrict__ XB,
                                               unsigned short* __restrict__ MEMS) {
    int ib = blockIdx.x;
    int i = ib >> 3, b = ib & 7;
    for (int c = 0; c < 2; ++c) {
        int col = threadIdx.x + c * 256;
        float s = 0.f;
#pragma unroll
        for (int t = 0; t < 16; ++t) s += XB[((size_t)((i * 16 + t) * NB + b)) * D + col];
        MEMS[(size_t)ib * D + col] = f2bf(s * (1.f / 16.f));
    }
}

// ---------------- LayerNorm: fp32 in, bf16 out (+optional fp32 out) ----------------
__global__ __launch_bounds__(256) void ln_k(const float* __restrict__ X,
                                            unsigned short* __restrict__ Y16,
                                            float* __restrict__ Yf,
                                            const float* __restrict__ g,
                                            const float* __restrict__ be, int dual) {
    int row = blockIdx.x;
    const float* x = X + (size_t)row * D;
    float v[2];
    float s = 0.f, ss = 0.f;
#pragma unroll
    for (int j = 0; j < 2; ++j) {
        v[j] = x[threadIdx.x + j * 256];
        s += v[j];
        ss = fmaf(v[j], v[j], ss);
    }
#pragma unroll
    for (int off = 32; off; off >>= 1) {
        s += __shfl_xor(s, off);
        ss += __shfl_xor(ss, off);
    }
    __shared__ float rs_[4], rss_[4];
    int w = threadIdx.x >> 6;
    if ((threadIdx.x & 63) == 0) {
        rs_[w] = s;
        rss_[w] = ss;
    }
    __syncthreads();
    s = rs_[0] + rs_[1] + rs_[2] + rs_[3];
    ss = rss_[0] + rss_[1] + rss_[2] + rss_[3];
    float mean = s * (1.f / D);
    float var = ss * (1.f / D) - mean * mean;
    float rstd = rsqrtf(var + 1e-5f);
#pragma unroll
    for (int j = 0; j < 2; ++j) {
        int col = threadIdx.x + j * 256;
        float y = (v[j] - mean) * rstd * g[col] + be[col];
        Y16[(size_t)row * D + col] = f2bf(y);
        if (dual) Yf[(size_t)row * D + col] = y;
    }
}

// ---------------- residual add + LN + mems-tanh fused ----------------
__global__ __launch_bounds__(256) void ln_res_k(const float* __restrict__ OUTB,
                                                float* __restrict__ SB,
                                                unsigned short* __restrict__ MEMS,
                                                unsigned short* __restrict__ Y16,
                                                const float* __restrict__ g,
                                                const float* __restrict__ be) {
    int row = blockIdx.x;
    if (row >= SROWS * NB) {
        int j = row - SROWS * NB;
#pragma unroll
        for (int c = 0; c < 2; ++c) {
            int col = threadIdx.x + c * 256;
            MEMS[(size_t)j * D + col] = f2bf(tanhf(OUTB[(size_t)row * D + col]));
        }
        return;
    }
    float v[2];
    float s = 0.f, ss = 0.f;
#pragma unroll
    for (int j = 0; j < 2; ++j) {
        int col = threadIdx.x + j * 256;
        float r = SB[(size_t)row * D + col] + OUTB[(size_t)row * D + col];
        SB[(size_t)row * D + col] = r;
        v[j] = r;
        s += r;
        ss = fmaf(r, r, ss);
    }
#pragma unroll
    for (int off = 32; off; off >>= 1) {
        s += __shfl_xor(s, off);
        ss += __shfl_xor(ss, off);
    }
    __shared__ float rs_[4], rss_[4];
    int w = threadIdx.x >> 6;
    if ((threadIdx.x & 63) == 0) {
        rs_[w] = s;
        rss_[w] = ss;
    }
    __syncthreads();
    s = rs_[0] + rs_[1] + rs_[2] + rs_[3];
    ss = rss_[0] + rss_[1] + rss_[2] + rss_[3];
    float mean = s * (1.f / D);
    float var = ss * (1.f / D) - mean * mean;
    float rstd = rsqrtf(var + 1e-5f);
#pragma unroll
    for (int j = 0; j < 2; ++j) {
        int col = threadIdx.x + j * 256;
        Y16[(size_t)row * D + col] = f2bf((v[j] - mean) * rstd * g[col] + be[col]);
    }
}

// ---------------- summary = per-segment mean of ln_utt (bf16) ----------------
__global__ __launch_bounds__(256) void summary_k(const unsigned short* __restrict__ LN16,
                                                 unsigned short* __restrict__ SUM16) {
    int ib = blockIdx.x;
    int i = ib >> 3, b = ib & 7;
    for (int c = 0; c < 2; ++c) {
        int col = threadIdx.x + c * 256;
        float s = 0.f;
#pragma unroll
        for (int t = 0; t < 16; ++t)
            s += bf2f(LN16[((size_t)((RT + i * 16 + t) * NB + b)) * D + col]);
        SUM16[(size_t)ib * D + col] = f2bf(s * (1.f / 16.f));
    }
}

// ---------------- 32x32 transpose + fp32->bf16 convert helper ----------------
__device__ inline void conv_tile(float (*tile)[33], const float* __restrict__ src, int srcN,
                                 int k0, int sn0, unsigned short* __restrict__ dst, int dstK,
                                 int dn0) {
    int t = threadIdx.x;
    int r = t >> 3, c4 = (t & 7) * 4;
    float4 v = *(const float4*)&src[(size_t)(k0 + r) * srcN + sn0 + c4];
    tile[r][c4 + 0] = v.x;
    tile[r][c4 + 1] = v.y;
    tile[r][c4 + 2] = v.z;
    tile[r][c4 + 3] = v.w;
    __syncthreads();
    ushort4 o;
    o.x = f2bf(tile[c4 + 0][r]);
    o.y = f2bf(tile[c4 + 1][r]);
    o.z = f2bf(tile[c4 + 2][r]);
    o.w = f2bf(tile[c4 + 3][r]);
    *(ushort4*)&dst[(size_t)(dn0 + r) * dstK + k0 + c4] = o;
}

// ---------------- per-layer weight conversion: fp32 KxN -> bf16 NxK ----------------
__global__ __launch_bounds__(256) void convw_k(const float* __restrict__ wq,
                                               const float* __restrict__ wk,
                                               const float* __restrict__ wv,
                                               const float* __restrict__ wo,
                                               const float* __restrict__ w1,
                                               const float* __restrict__ w2,
                                               const float* __restrict__ bq,
                                               const float* __restrict__ bk,
                                               const float* __restrict__ bv,
                                               unsigned short* __restrict__ WQKV,
                                               unsigned short* __restrict__ WO16,
                                               unsigned short* __restrict__ W1T,
                                               unsigned short* __restrict__ W2T,
                                               float* __restrict__ BQKV, int l) {
    __shared__ float tile[32][33];
    int t = blockIdx.x;
    if (t == 0) {
        for (int i = threadIdx.x; i < 1536; i += 256)
            BQKV[i] = i < 512 ? bq[l * 512 + i]
                              : (i < 1024 ? bk[l * 512 + i - 512] : bv[l * 512 + i - 1024]);
    }
    if (t < 768) {
        int tn = t % 48, tk = t / 48;
        int n0 = tn * 32, k0 = tk * 32;
        const float* src;
        int sn0;
        if (n0 < 512) { src = wq + (size_t)l * 262144; sn0 = n0; }
        else if (n0 < 1024) { src = wk + (size_t)l * 262144; sn0 = n0 - 512; }
        else { src = wv + (size_t)l * 262144; sn0 = n0 - 1024; }
        conv_tile(tile, src, 512, k0, sn0, WQKV, 512, n0);
    } else if (t < 1024) {
        int tt = t - 768;
        int n0 = (tt % 16) * 32, k0 = (tt / 16) * 32;
        conv_tile(tile, wo + (size_t)l * 262144, 512, k0, n0, WO16, 512, n0);
    } else if (t < 2048) {
        int tt = t - 1024;
        int n0 = (tt % 64) * 32, k0 = (tt / 64) * 32;
        conv_tile(tile, w1 + (size_t)l * 1048576, 2048, k0, n0, W1T, 512, n0);
    } else {
        int tt = t - 2048;
        int n0 = (tt % 16) * 32, k0 = (tt / 16) * 32;
        conv_tile(tile, w2 + (size_t)l * 1048576, 512, k0, n0, W2T, 2048, n0);
    }
}

__global__ __launch_bounds__(256) void convout_k(const float* __restrict__ w_out,
                                                 unsigned short* __restrict__ WOUT16) {
    __shared__ float tile[32][33];
    int t = blockIdx.x;
    int n0 = (t % 32) * 32, k0 = (t / 32) * 32;
    conv_tile(tile, w_out, 1024, k0, n0, WOUT16, 512, n0);
}

// ---------------- bf16 MFMA GEMM, 64x64 tile, BK=64, register double-buffer ----------
// flags: 1 = relu, 2 = add into fp32 C, 4 = bf16 output, 8 = atomicAdd into fp32 C
__global__ __launch_bounds__(256) void gemm16_k(const unsigned short* __restrict__ A,
                                                const unsigned short* __restrict__ BT,
                                                const float* __restrict__ bias,
                                                void* __restrict__ Cp, int M, int N, int K,
                                                int Kchunk, int flags) {
    __shared__ unsigned short As[2][64][40];
    __shared__ unsigned short Bs[2][64][40];
    int tid = threadIdx.x;
    int wave = tid >> 6, lane = tid & 63;
    int wm = wave >> 1, wn = wave & 1;
    int quad = lane >> 4, sub = lane & 15;
    int m0 = blockIdx.y * 64, n0 = blockIdx.x * 64;
    int kb = blockIdx.z * Kchunk, ke = kb + Kchunk;

    int lrow = tid >> 3, lkc = tid & 7;
    int lrow2 = lrow + 32;
    int lkh = lkc >> 2, lkl = lkc & 3;

    f32x4 acc[2][2] = {};
    int4 ar0, ar1, br0, br1;

    auto loadT = [&](int k0) {
        int gr0 = m0 + lrow, gr1 = m0 + lrow2;
        ar0 = (gr0 < M) ? *(const int4*)&A[(size_t)gr0 * K + k0 + lkc * 8] : make_int4(0, 0, 0, 0);
        ar1 = (gr1 < M) ? *(const int4*)&A[(size_t)gr1 * K + k0 + lkc * 8] : make_int4(0, 0, 0, 0);
        br0 = *(const int4*)&BT[(size_t)(n0 + lrow) * K + k0 + lkc * 8];
        br1 = *(const int4*)&BT[(size_t)(n0 + lrow2) * K + k0 + lkc * 8];
    };
    auto storeT = [&]() {
        *(int4*)&As[lkh][lrow][lkl * 8] = ar0;
        *(int4*)&As[lkh][lrow2][lkl * 8] = ar1;
        *(int4*)&Bs[lkh][lrow][lkl * 8] = br0;
        *(int4*)&Bs[lkh][lrow2][lkl * 8] = br1;
    };
    auto compute = [&]() {
#pragma unroll
        for (int ks = 0; ks < 2; ++ks) {
            bf16x8 af[2], bf[2];
#pragma unroll
            for (int mi = 0; mi < 2; ++mi)
                af[mi] = *(const bf16x8*)&As[ks][wm * 32 + mi * 16 + sub][quad * 8];
#pragma unroll
            for (int ni = 0; ni < 2; ++ni)
                bf[ni] = *(const bf16x8*)&Bs[ks][wn * 32 + ni * 16 + sub][quad * 8];
#pragma unroll
            for (int mi = 0; mi < 2; ++mi)
#pragma unroll
                for (int ni = 0; ni < 2; ++ni)
                    acc[mi][ni] = __builtin_amdgcn_mfma_f32_16x16x32_bf16(af[mi], bf[ni],
                                                                          acc[mi][ni], 0, 0, 0);
        }
    };

    loadT(kb);
    storeT();
    __syncthreads();
    for (int k0 = kb + 64; k0 < ke; k0 += 64) {
        loadT(k0);
        compute();
        __syncthreads();
        storeT();
        __syncthreads();
    }
    compute();

    bool relu = flags & 1, addc = flags & 2, obf = flags & 4, atom = flags & 8;
    bool addbias = !atom || blockIdx.z == 0;
    float* Cf = (float*)Cp;
    unsigned short* Ch = (unsigned short*)Cp;
#pragma unroll
    for (int mi = 0; mi < 2; ++mi) {
#pragma unroll
        for (int ni = 0; ni < 2; ++ni) {
#pragma unroll
            for (int r = 0; r < 4; ++r) {
                int row = m0 + wm * 32 + mi * 16 + quad * 4 + r;
                int col = n0 + wn * 32 + ni * 16 + sub;
                if (row < M) {
                    float v = acc[mi][ni][r] + (addbias ? bias[col] : 0.f);
                    if (relu) v = fmaxf(v, 0.f);
                    size_t idx = (size_t)row * N + col;
                    if (obf) {
                        Ch[idx] = f2bf(v);
                    } else if (atom) {
                        atomicAdd(&Cf[idx], v);
                    } else {
                        if (addc) v += Cf[idx];
                        Cf[idx] = v;
                    }
                }
            }
        }
    }
}

// ---------------- attention: one 256-thread block per (qrow, b), all 8 heads ----------------
__global__ __launch_bounds__(256) void attn_k(const unsigned short* __restrict__ QKV,
                                              unsigned short* __restrict__ ATT,
                                              const int* __restrict__ lrw) {
    int tid = threadIdx.x;
    int qrow = blockIdx.x;
    int b = blockIdx.y;

    int i, is_sum;
    if (qrow < RT) {
        i = qrow >> 2;
        is_sum = 0;
    } else if (qrow < RT + UU) {
        i = (qrow - RT) >> 4;
        is_sum = 0;
    } else {
        i = qrow - (RT + UU);
        is_sum = 1;
    }
    int ms = (i > 4) ? (i - 4) : 0;
    int n_mem = is_sum ? 0 : (i - ms);
    int us = (i * 16 - 32 > 0) ? (i * 16 - 32) : 0;
    int ue = (i + 1) * 16;
    int total = n_mem + 4 + (ue - us);
    int klen = KN + lrw[b] - lrw[NB];

    __shared__ float qs[512];
    __shared__ float sc[H][64];
    __shared__ int kks[64];

    // Phase A: q row -> LDS (scaled); key index list -> LDS
    {
        const unsigned int* qrp =
            (const unsigned int*)&QKV[(size_t)(120 + qrow * NB + b) * 1536];
        unsigned int u = qrp[tid];
        qs[2 * tid] = __uint_as_float(u << 16) * QSCALE;
        qs[2 * tid + 1] = __uint_as_float(u & 0xFFFF0000u) * QSCALE;
    }
    if (tid < 64) {
        int kk = -1;
        if (tid < total) {
            if (tid < n_mem)
                kk = ms + tid;
            else if (tid < n_mem + 4)
                kk = 15 + i * 4 + (tid - n_mem);
            else
                kk = 79 + us + (tid - n_mem - 4);
        }
        kks[tid] = kk;
    }
    __syncthreads();

    // Phase B: scores for all (head, key) pairs
#pragma unroll
    for (int rep = 0; rep < 2; ++rep) {
        int p = rep * 256 + tid;
        int h = p >> 6, j = p & 63;
        int kk = kks[j];
        float s = NEGV;
        if (kk >= 0 && kk < klen) {
            const int4* kr = (const int4*)&QKV[(size_t)(kk * NB + b) * 1536 + 512 + h * DH];
            const float* qh = &qs[h * DH];
            float accd = 0.f;
#pragma unroll
            for (int c = 0; c < 8; ++c) {
                int4 kv = kr[c];
                const int uu[4] = {kv.x, kv.y, kv.z, kv.w};
#pragma unroll
                for (int jj = 0; jj < 4; ++jj) {
                    float lo = __uint_as_float(((unsigned)uu[jj]) << 16);
                    float hi = __uint_as_float(((unsigned)uu[jj]) & 0xFFFF0000u);
                    accd = fmaf(lo, qh[c * 8 + jj * 2], accd);
                    accd = fmaf(hi, qh[c * 8 + jj * 2 + 1], accd);
                }
            }
            s = accd;
        }
        sc[h][j] = s;
    }
    __syncthreads();

    // Phase C: softmax per head (wave w handles heads w and w+4)
    {
        int wv = tid >> 6, lane = tid & 63;
#pragma unroll
        for (int hh = 0; hh < 2; ++hh) {
            int h = wv + hh * 4;
            float s = sc[h][lane];
            float m = s;
#pragma unroll
            for (int off = 32; off; off >>= 1) m = fmaxf(m, __shfl_xor(m, off));
            float p = __expf(s - m);
            float sum = p;
#pragma unroll
            for (int off = 32; off; off >>= 1) sum += __shfl_xor(sum, off);
            sc[h][lane] = p / sum;
        }
    }
    __syncthreads();

    // Phase D: PV accumulate; thread owns cols 2*tid, 2*tid+1 (head = tid>>5)
    {
        int h = tid >> 5;
        const float* ph = sc[h];
        float a0 = 0.f, a1 = 0.f;
        const unsigned short* vbase = QKV + (size_t)b * 1536 + 1024 + 2 * tid;
#pragma unroll 4
        for (int j = 0; j < total; ++j) {
            int kkj = kks[j];
            unsigned int u = *(const unsigned int*)&vbase[(size_t)kkj * (NB * 1536)];
            float p = ph[j];
            a0 = fmaf(p, __uint_as_float(u << 16), a0);
            a1 = fmaf(p, __uint_as_float(u & 0xFFFF0000u), a1);
        }
        unsigned int o = ((unsigned int)f2bf(a0)) | (((unsigned int)f2bf(a1)) << 16);
        *(unsigned int*)&ATT[(size_t)(qrow * NB + b) * D + 2 * tid] = o;
    }
}

// ---------------- final LN (width 1024) with permuted output ----------------
__global__ __launch_bounds__(256) void final_ln_k(const float* __restrict__ Yb,
                                                  const float* __restrict__ g,
                                                  const float* __restrict__ be,
                                                  float* __restrict__ out) {
    int row = blockIdx.x;
    int u = row >> 3, b = row & 7;
    const float* x = Yb + (size_t)row * OUTD;
    float v[4];
    float s = 0.f, ss = 0.f;
#pragma unroll
    for (int j = 0; j < 4; ++j) {
        v[j] = x[threadIdx.x + j * 256];
        s += v[j];
        ss = fmaf(v[j], v[j], ss);
    }
#pragma unroll
    for (int off = 32; off; off >>= 1) {
        s += __shfl_xor(s, off);
        ss += __shfl_xor(ss, off);
    }
    __shared__ float rs_[4], rss_[4];
    int w = threadIdx.x >> 6;
    if ((threadIdx.x & 63) == 0) {
        rs_[w] = s;
        rss_[w] = ss;
    }
    __syncthreads();
    s = rs_[0] + rs_[1] + rs_[2] + rs_[3];
    ss = rss_[0] + rss_[1] + rss_[2] + rss_[3];
    float mean = s * (1.f / OUTD);
    float var = ss * (1.f / OUTD) - mean * mean;
    float rstd = rsqrtf(var + 1e-5f);
    float* o = out + ((size_t)(b * 256 + u)) * OUTD;
#pragma unroll
    for (int j = 0; j < 4; ++j) {
        int col = threadIdx.x + j * 256;
        o[col] = (v[j] - mean) * rstd * g[col] + be[col];
    }
}

extern "C" void kernel_launch(void* const* d_in, const int* in_sizes, int n_in, void* d_out,
                              int out_size, void* d_ws, size_t ws_size, hipStream_t stream) {
    (void)in_sizes;
    (void)n_in;
    (void)out_size;
    (void)ws_size;
    const float* input = (const float*)d_in[0];
    const int* lengths = (const int*)d_in[1];
    const float* w_in = (const float*)d_in[2];
    const float* ln_in_g = (const float*)d_in[3];
    const float* ln_in_b = (const float*)d_in[4];
    const float* wq = (const float*)d_in[5];
    const float* bq = (const float*)d_in[6];
    const float* wk = (const float*)d_in[7];
    const float* bk = (const float*)d_in[8];
    const float* wv = (const float*)d_in[9];
    const float* bv = (const float*)d_in[10];
    const float* wo = (const float*)d_in[11];
    const float* bo = (const float*)d_in[12];
    const float* ff_g = (const float*)d_in[13];
    const float* ff_b = (const float*)d_in[14];
    const float* w1 = (const float*)d_in[15];
    const float* b1 = (const float*)d_in[16];
    const float* w2 = (const float*)d_in[17];
    const float* b2 = (const float*)d_in[18];
    const float* lo_g = (const float*)d_in[19];
    const float* lo_b = (const float*)d_in[20];
    const float* w_out = (const float*)d_in[21];
    const float* b_out = (const float*)d_in[22];
    const float* lng = (const float*)d_in[23];
    const float* lnb = (const float*)d_in[24];
    float* out = (float*)d_out;

    char* wsc = (char*)d_ws;
    size_t off = 0;
    auto alloc = [&](size_t bytes) {
        char* p = wsc + off;
        off += (bytes + 255) & ~(size_t)255;
        return p;
    };
    unsigned short* ACT16 = (unsigned short*)alloc(2808ULL * 512 * 2);
    unsigned short* ATT16 = (unsigned short*)alloc(2688ULL * 512 * 2);
    unsigned short* HB16 = (unsigned short*)alloc(2560ULL * 2048 * 2);
    unsigned short* QKVB = (unsigned short*)alloc(2808ULL * 1536 * 2);
    float* SB = (float*)alloc(2560ULL * 512 * 4);
    unsigned short* WQKV16 = (unsigned short*)alloc(1536ULL * 512 * 2);
    unsigned short* WO16 = (unsigned short*)alloc(512ULL * 512 * 2);
    unsigned short* W1T = (unsigned short*)alloc(2048ULL * 512 * 2);
    unsigned short* W2T = (unsigned short*)alloc(512ULL * 2048 * 2);
    unsigned short* WOUT16 = (unsigned short*)alloc(1024ULL * 512 * 2);
    float* BQKV = (float*)alloc(1536 * 4);
    int* LRW = (int*)alloc(64);

    unsigned short* MEMS16 = ACT16;               // 120 rows
    unsigned short* LNB16 = ACT16 + 120 * 512;    // 2560 rows
    unsigned short* SUMB16 = ACT16 + 2680 * 512;  // 128 rows
    float* XB = (float*)QKVB;    // init-time alias
    float* OUTB = (float*)QKVB;  // post-attention alias
    float* HBf = (float*)QKVB;   // final-proj alias

    lr_k<<<1, 64, 0, stream>>>(lengths, LRW, out + (size_t)NB * 256 * 1024);
    convout_k<<<512, 256, 0, stream>>>(w_out, WOUT16);
    inproj_k<<<TR * NB, 128, 0, stream>>>(input, w_in, XB);
    initstate_k<<<SROWS * NB, 256, 0, stream>>>(XB, SB);
    mems0_k<<<15 * NB, 256, 0, stream>>>(XB, MEMS16);

    for (int l = 0; l < LAYERS; ++l) {
        convw_k<<<3072, 256, 0, stream>>>(wq, wk, wv, wo, w1, w2, bq, bk, bv, WQKV16, WO16, W1T,
                                          W2T, BQKV, l);
        ln_k<<<SROWS * NB, 256, 0, stream>>>(SB, LNB16, SB, ln_in_g + l * D, ln_in_b + l * D, 0);
        summary_k<<<NSEG * NB, 256, 0, stream>>>(LNB16, SUMB16);
        // fused QKV: A = [MEMS][LN][SUM] (2808 rows), N = 1536
        gemm16_k<<<dim3(24, 44, 1), 256, 0, stream>>>(ACT16, WQKV16, BQKV, QKVB, 2808, 1536, 512,
                                                      512, 4);
        attn_k<<<dim3(QN, NB), 256, 0, stream>>>(QKVB, ATT16, LRW);
        gemm16_k<<<dim3(8, 42, 1), 256, 0, stream>>>(ATT16, WO16, bo + l * D, OUTB, QN * NB, D,
                                                     D, D, 0);
        ln_res_k<<<(SROWS + 15) * NB, 256, 0, stream>>>(OUTB, SB, MEMS16, LNB16, ff_g + l * D,
                                                        ff_b + l * D);
        gemm16_k<<<dim3(32, 40, 1), 256, 0, stream>>>(LNB16, W1T, b1 + l * FFN_D, HB16,
                                                      SROWS * NB, FFN_D, D, D, 1 | 4);
        gemm16_k<<<dim3(8, 40, 4), 256, 0, stream>>>(HB16, W2T, b2 + l * D, SB, SROWS * NB, D,
                                                     FFN_D, 512, 8);
        ln_k<<<SROWS * NB, 256, 0, stream>>>(SB, LNB16, SB, lo_g + l * D, lo_b + l * D, 1);
    }
    // final projection of utt rows (LNB16 rows 64*NB ..) then LN -> out
    gemm16_k<<<dim3(16, 32, 1), 256, 0, stream>>>(LNB16 + (size_t)RT * NB * D, WOUT16, b_out,
                                                  HBf, UU * NB, OUTD, D, D, 0);
    final_ln_k<<<UU * NB, 256, 0, stream>>>(HBf, lng, lnb, out);
}

// Round 5
// 1113.404 us; speedup vs baseline: 4.2363x; 1.0740x over previous
//
#include <hip/hip_runtime.h>
#include <math.h>

#define NB 8
#define D 512
#define H 8
#define DH 64
#define NSEG 16
#define RT 64
#define UU 256
#define QN 336
#define KN 335
#define SROWS 320
#define FFN_D 2048
#define LAYERS 8
#define OUTD 1024
#define TR 260
#define NEGV (-100000000.0f)
#define QSCALE 0.125f

typedef __attribute__((ext_vector_type(8))) short bf16x8;
typedef __attribute__((ext_vector_type(4))) float f32x4;

__device__ inline unsigned short f2bf(float f) {
    union { float f; unsigned int u; } v; v.f = f;
    unsigned int u = v.u;
    unsigned int r = (u + 0x7FFFu + ((u >> 16) & 1u)) >> 16;
    return (unsigned short)r;
}
__device__ inline float bf2f(unsigned short h) {
    union { unsigned int u; float f; } v; v.u = ((unsigned int)h) << 16;
    return v.f;
}

// 16-byte global -> LDS async DMA. LDS dest = wave-uniform base + lane*16.
__device__ inline void async16(const void* g, void* l) {
    __builtin_amdgcn_global_load_lds((const __attribute__((address_space(1))) void*)g,
                                     (__attribute__((address_space(3))) void*)l, 16, 0, 0);
}

// ---------------- lr + max ----------------
__global__ void lr_k(const int* __restrict__ lengths, int* __restrict__ lrw,
                     float* __restrict__ out_lr) {
    if (threadIdx.x == 0) {
        int mx = 0;
        for (int b = 0; b < NB; ++b) {
            int v = lengths[b] >> 2;
            lrw[b] = v;
            out_lr[b] = (float)v;
            if (v > mx) mx = v;
        }
        lrw[NB] = mx;
    }
}

// ---------------- input projection + reshape to (t,b,512) ----------------
__global__ __launch_bounds__(128) void inproj_k(const float* __restrict__ input,
                                                const float* __restrict__ w_in,
                                                float* __restrict__ XB) {
    __shared__ float wl[80 * 128];
    __shared__ float il[4 * 80];
    int tid = threadIdx.x;
    int t = blockIdx.x >> 3;
    int b = blockIdx.x & 7;
    for (int i = tid; i < 80 * 128; i += 128) wl[i] = w_in[i];
    const float* inp = input + ((size_t)b * 1040 + (size_t)t * 4) * 80;
    for (int i = tid; i < 320; i += 128) il[i] = inp[i];
    __syncthreads();
    float* xrow = XB + ((size_t)(t * NB + b)) * D;
#pragma unroll
    for (int c = 0; c < 4; ++c) {
        float acc = 0.f;
        for (int i = 0; i < 80; ++i) acc = fmaf(il[c * 80 + i], wl[i * 128 + tid], acc);
        xrow[c * 128 + tid] = acc;
    }
}

// ---------------- init state S = [rc(64), utt(256)] (fp32) ----------------
__global__ __launch_bounds__(256) void initstate_k(const float* __restrict__ XB,
                                                   float* __restrict__ S) {
    int r = blockIdx.x;
    int srow = r >> 3, b = r & 7;
    int src;
    if (srow < RT) {
        int i = srow >> 2, jj = srow & 3;
        src = (i < 15 ? (i + 1) * 16 : 256) + jj;
    } else {
        src = srow - RT;
    }
    const float* xr = XB + ((size_t)(src * NB + b)) * D;
    float* sr = S + (size_t)r * D;
    sr[threadIdx.x] = xr[threadIdx.x];
    sr[threadIdx.x + 256] = xr[threadIdx.x + 256];
}

// ---------------- initial mems -> bf16 ----------------
__global__ __launch_bounds__(256) void mems0_k(const float* __restrict__ XB,
                                               unsigned short* __restrict__ MEMS) {
    int ib = blockIdx.x;
    int i = ib >> 3, b = ib & 7;
    for (int c = 0; c < 2; ++c) {
        int col = threadIdx.x + c * 256;
        float s = 0.f;
#pragma unroll
        for (int t = 0; t < 16; ++t) s += XB[((size_t)((i * 16 + t) * NB + b)) * D + col];
        MEMS[(size_t)ib * D + col] = f2bf(s * (1.f / 16.f));
    }
}

// ---------------- LayerNorm: fp32 in, bf16 out (+optional fp32 out) ----------------
__global__ __launch_bounds__(256) void ln_k(const float* __restrict__ X,
                                            unsigned short* __restrict__ Y16,
                                            float* __restrict__ Yf,
                                            const float* __restrict__ g,
                                            const float* __restrict__ be, int dual) {
    int row = blockIdx.x;
    const float* x = X + (size_t)row * D;
    float v[2];
    float s = 0.f, ss = 0.f;
#pragma unroll
    for (int j = 0; j < 2; ++j) {
        v[j] = x[threadIdx.x + j * 256];
        s += v[j];
        ss = fmaf(v[j], v[j], ss);
    }
#pragma unroll
    for (int off = 32; off; off >>= 1) {
        s += __shfl_xor(s, off);
        ss += __shfl_xor(ss, off);
    }
    __shared__ float rs_[4], rss_[4];
    int w = threadIdx.x >> 6;
    if ((threadIdx.x & 63) == 0) {
        rs_[w] = s;
        rss_[w] = ss;
    }
    __syncthreads();
    s = rs_[0] + rs_[1] + rs_[2] + rs_[3];
    ss = rss_[0] + rss_[1] + rss_[2] + rss_[3];
    float mean = s * (1.f / D);
    float var = ss * (1.f / D) - mean * mean;
    float rstd = rsqrtf(var + 1e-5f);
#pragma unroll
    for (int j = 0; j < 2; ++j) {
        int col = threadIdx.x + j * 256;
        float y = (v[j] - mean) * rstd * g[col] + be[col];
        Y16[(size_t)row * D + col] = f2bf(y);
        if (dual) Yf[(size_t)row * D + col] = y;
    }
}

// ---------------- residual add + LN + mems-tanh fused ----------------
__global__ __launch_bounds__(256) void ln_res_k(const float* __restrict__ OUTB,
                                                float* __restrict__ SB,
                                                unsigned short* __restrict__ MEMS,
                                                unsigned short* __restrict__ Y16,
                                                const float* __restrict__ g,
                                                const float* __restrict__ be) {
    int row = blockIdx.x;
    if (row >= SROWS * NB) {
        int j = row - SROWS * NB;
#pragma unroll
        for (int c = 0; c < 2; ++c) {
            int col = threadIdx.x + c * 256;
            MEMS[(size_t)j * D + col] = f2bf(tanhf(OUTB[(size_t)row * D + col]));
        }
        return;
    }
    float v[2];
    float s = 0.f, ss = 0.f;
#pragma unroll
    for (int j = 0; j < 2; ++j) {
        int col = threadIdx.x + j * 256;
        float r = SB[(size_t)row * D + col] + OUTB[(size_t)row * D + col];
        SB[(size_t)row * D + col] = r;
        v[j] = r;
        s += r;
        ss = fmaf(r, r, ss);
    }
#pragma unroll
    for (int off = 32; off; off >>= 1) {
        s += __shfl_xor(s, off);
        ss += __shfl_xor(ss, off);
    }
    __shared__ float rs_[4], rss_[4];
    int w = threadIdx.x >> 6;
    if ((threadIdx.x & 63) == 0) {
        rs_[w] = s;
        rss_[w] = ss;
    }
    __syncthreads();
    s = rs_[0] + rs_[1] + rs_[2] + rs_[3];
    ss = rss_[0] + rss_[1] + rss_[2] + rss_[3];
    float mean = s * (1.f / D);
    float var = ss * (1.f / D) - mean * mean;
    float rstd = rsqrtf(var + 1e-5f);
#pragma unroll
    for (int j = 0; j < 2; ++j) {
        int col = threadIdx.x + j * 256;
        Y16[(size_t)row * D + col] = f2bf((v[j] - mean) * rstd * g[col] + be[col]);
    }
}

// ---------------- summary = per-segment mean of ln_utt (bf16) ----------------
__global__ __launch_bounds__(256) void summary_k(const unsigned short* __restrict__ LN16,
                                                 unsigned short* __restrict__ SUM16) {
    int ib = blockIdx.x;
    int i = ib >> 3, b = ib & 7;
    for (int c = 0; c < 2; ++c) {
        int col = threadIdx.x + c * 256;
        float s = 0.f;
#pragma unroll
        for (int t = 0; t < 16; ++t)
            s += bf2f(LN16[((size_t)((RT + i * 16 + t) * NB + b)) * D + col]);
        SUM16[(size_t)ib * D + col] = f2bf(s * (1.f / 16.f));
    }
}

// ---------------- 32x32 transpose + fp32->bf16 convert helper ----------------
__device__ inline void conv_tile(float (*tile)[33], const float* __restrict__ src, int srcN,
                                 int k0, int sn0, unsigned short* __restrict__ dst, int dstK,
                                 int dn0) {
    int t = threadIdx.x;
    int r = t >> 3, c4 = (t & 7) * 4;
    float4 v = *(const float4*)&src[(size_t)(k0 + r) * srcN + sn0 + c4];
    tile[r][c4 + 0] = v.x;
    tile[r][c4 + 1] = v.y;
    tile[r][c4 + 2] = v.z;
    tile[r][c4 + 3] = v.w;
    __syncthreads();
    ushort4 o;
    o.x = f2bf(tile[c4 + 0][r]);
    o.y = f2bf(tile[c4 + 1][r]);
    o.z = f2bf(tile[c4 + 2][r]);
    o.w = f2bf(tile[c4 + 3][r]);
    *(ushort4*)&dst[(size_t)(dn0 + r) * dstK + k0 + c4] = o;
}

// ---------------- ALL-layer weight conversion (one shot): fp32 KxN -> bf16 NxK ----------
__global__ __launch_bounds__(256) void convw_all_k(const float* __restrict__ wq,
                                                   const float* __restrict__ wk,
                                                   const float* __restrict__ wv,
                                                   const float* __restrict__ wo,
                                                   const float* __restrict__ w1,
                                                   const float* __restrict__ w2,
                                                   const float* __restrict__ bq,
                                                   const float* __restrict__ bk,
                                                   const float* __restrict__ bv,
                                                   const float* __restrict__ w_out,
                                                   unsigned short* __restrict__ WQKV,
                                                   unsigned short* __restrict__ WO16,
                                                   unsigned short* __restrict__ W1T,
                                                   unsigned short* __restrict__ W2T,
                                                   unsigned short* __restrict__ WOUT16,
                                                   float* __restrict__ BQKV) {
    __shared__ float tile[32][33];
    int tb = blockIdx.x;
    if (tb >= LAYERS * 3072) {
        int t = tb - LAYERS * 3072;  // 512 tiles for w_out (512x1024 -> 1024x512)
        int n0 = (t % 32) * 32, k0 = (t / 32) * 32;
        conv_tile(tile, w_out, 1024, k0, n0, WOUT16, 512, n0);
        return;
    }
    int l = tb / 3072, t = tb % 3072;
    if (t == 0) {
        for (int i = threadIdx.x; i < 1536; i += 256)
            BQKV[l * 1536 + i] = i < 512 ? bq[l * 512 + i]
                                         : (i < 1024 ? bk[l * 512 + i - 512]
                                                     : bv[l * 512 + i - 1024]);
    }
    if (t < 768) {
        int tn = t % 48, tk = t / 48;
        int n0 = tn * 32, k0 = tk * 32;
        const float* src;
        int sn0;
        if (n0 < 512) { src = wq + (size_t)l * 262144; sn0 = n0; }
        else if (n0 < 1024) { src = wk + (size_t)l * 262144; sn0 = n0 - 512; }
        else { src = wv + (size_t)l * 262144; sn0 = n0 - 1024; }
        conv_tile(tile, src, 512, k0, sn0, WQKV + (size_t)l * 1536 * 512, 512, n0);
    } else if (t < 1024) {
        int tt = t - 768;
        int n0 = (tt % 16) * 32, k0 = (tt / 16) * 32;
        conv_tile(tile, wo + (size_t)l * 262144, 512, k0, n0, WO16 + (size_t)l * 512 * 512, 512,
                  n0);
    } else if (t < 2048) {
        int tt = t - 1024;
        int n0 = (tt % 64) * 32, k0 = (tt / 64) * 32;
        conv_tile(tile, w1 + (size_t)l * 1048576, 2048, k0, n0, W1T + (size_t)l * 2048 * 512, 512,
                  n0);
    } else {
        int tt = t - 2048;
        int n0 = (tt % 16) * 32, k0 = (tt / 16) * 32;
        conv_tile(tile, w2 + (size_t)l * 1048576, 512, k0, n0, W2T + (size_t)l * 512 * 2048, 2048,
                  n0);
    }
}

// ---------------- bf16 MFMA GEMM, 64x64 tile, BK=64, async LDS + XOR swizzle ----------
// LDS layout: tile row r (64 bf16 = 8 chunks of 16B); global chunk c stored at
// LDS chunk ch = c ^ (r&7). DMA writes are lane-contiguous; ds_read_b128 spreads
// over all 32 banks (2-way aliasing only = free).
// flags: 1 = relu, 2 = add into fp32 C, 4 = bf16 output, 8 = atomicAdd into fp32 C
__global__ __launch_bounds__(256) void gemm16_k(const unsigned short* __restrict__ A,
                                                const unsigned short* __restrict__ BT,
                                                const float* __restrict__ bias,
                                                void* __restrict__ Cp, int M, int N, int K,
                                                int Kchunk, int flags) {
    __shared__ unsigned short As[64 * 64];
    __shared__ unsigned short Bs[64 * 64];
    int tid = threadIdx.x;
    int wave = tid >> 6, lane = tid & 63;
    int wm = wave >> 1, wn = wave & 1;
    int quad = lane >> 4, sub = lane & 15;
    int m0 = blockIdx.y * 64, n0 = blockIdx.x * 64;
    int kb = blockIdx.z * Kchunk, ke = kb + Kchunk;

    // staging: slot s covers LDS chunk s = row*8+ch; wave handles slots [wave*128, wave*128+128)
    int s0 = wave * 128 + lane;
    int s1 = s0 + 64;
    int r0 = s0 >> 3, c0 = (s0 & 7) ^ (r0 & 7);
    int r1 = s1 >> 3, c1 = (s1 & 7) ^ (r1 & 7);
    const unsigned short* gA0 = A + (size_t)(m0 + r0) * K + c0 * 8 + kb;
    const unsigned short* gA1 = A + (size_t)(m0 + r1) * K + c1 * 8 + kb;
    const unsigned short* gB0 = BT + (size_t)(n0 + r0) * K + c0 * 8 + kb;
    const unsigned short* gB1 = BT + (size_t)(n0 + r1) * K + c1 * 8 + kb;
    unsigned short* lA0 = &As[(wave * 128) * 8];
    unsigned short* lA1 = &As[(wave * 128 + 64) * 8];
    unsigned short* lB0 = &Bs[(wave * 128) * 8];
    unsigned short* lB1 = &Bs[(wave * 128 + 64) * 8];

    int rowA0 = wm * 32 + sub, rowA1 = rowA0 + 16;
    int rowB0 = wn * 32 + sub, rowB1 = rowB0 + 16;

    f32x4 acc[2][2] = {};
    for (int k0 = 0; k0 < Kchunk; k0 += 64) {
        async16(gA0 + k0, lA0);
        async16(gA1 + k0, lA1);
        async16(gB0 + k0, lB0);
        async16(gB1 + k0, lB1);
        __syncthreads();
#pragma unroll
        for (int ks = 0; ks < 2; ++ks) {
            int cc = ks * 4 + quad;
            bf16x8 af0 = *(const bf16x8*)&As[rowA0 * 64 + ((cc ^ (rowA0 & 7)) * 8)];
            bf16x8 af1 = *(const bf16x8*)&As[rowA1 * 64 + ((cc ^ (rowA1 & 7)) * 8)];
            bf16x8 bf0 = *(const bf16x8*)&Bs[rowB0 * 64 + ((cc ^ (rowB0 & 7)) * 8)];
            bf16x8 bf1 = *(const bf16x8*)&Bs[rowB1 * 64 + ((cc ^ (rowB1 & 7)) * 8)];
            acc[0][0] = __builtin_amdgcn_mfma_f32_16x16x32_bf16(af0, bf0, acc[0][0], 0, 0, 0);
            acc[0][1] = __builtin_amdgcn_mfma_f32_16x16x32_bf16(af0, bf1, acc[0][1], 0, 0, 0);
            acc[1][0] = __builtin_amdgcn_mfma_f32_16x16x32_bf16(af1, bf0, acc[1][0], 0, 0, 0);
            acc[1][1] = __builtin_amdgcn_mfma_f32_16x16x32_bf16(af1, bf1, acc[1][1], 0, 0, 0);
        }
        __syncthreads();
    }
    (void)ke;

    bool relu = flags & 1, addc = flags & 2, obf = flags & 4, atom = flags & 8;
    bool addbias = !atom || blockIdx.z == 0;
    float* Cf = (float*)Cp;
    unsigned short* Ch = (unsigned short*)Cp;
#pragma unroll
    for (int mi = 0; mi < 2; ++mi) {
#pragma unroll
        for (int ni = 0; ni < 2; ++ni) {
#pragma unroll
            for (int r = 0; r < 4; ++r) {
                int row = m0 + wm * 32 + mi * 16 + quad * 4 + r;
                int col = n0 + wn * 32 + ni * 16 + sub;
                if (row < M) {
                    float v = acc[mi][ni][r] + (addbias ? bias[col] : 0.f);
                    if (relu) v = fmaxf(v, 0.f);
                    size_t idx = (size_t)row * N + col;
                    if (obf) {
                        Ch[idx] = f2bf(v);
                    } else if (atom) {
                        atomicAdd(&Cf[idx], v);
                    } else {
                        if (addc) v += Cf[idx];
                        Cf[idx] = v;
                    }
                }
            }
        }
    }
}

// ---------------- attention: one 256-thread block per (qrow, b), all 8 heads ----------------
__global__ __launch_bounds__(256) void attn_k(const unsigned short* __restrict__ QKV,
                                              unsigned short* __restrict__ ATT,
                                              const int* __restrict__ lrw) {
    int tid = threadIdx.x;
    int qrow = blockIdx.x;
    int b = blockIdx.y;

    int i, is_sum;
    if (qrow < RT) {
        i = qrow >> 2;
        is_sum = 0;
    } else if (qrow < RT + UU) {
        i = (qrow - RT) >> 4;
        is_sum = 0;
    } else {
        i = qrow - (RT + UU);
        is_sum = 1;
    }
    int ms = (i > 4) ? (i - 4) : 0;
    int n_mem = is_sum ? 0 : (i - ms);
    int us = (i * 16 - 32 > 0) ? (i * 16 - 32) : 0;
    int ue = (i + 1) * 16;
    int total = n_mem + 4 + (ue - us);
    int klen = KN + lrw[b] - lrw[NB];

    __shared__ float qs[512];
    __shared__ float sc[H][64];
    __shared__ int kks[64];

    {
        const unsigned int* qrp =
            (const unsigned int*)&QKV[(size_t)(120 + qrow * NB + b) * 1536];
        unsigned int u = qrp[tid];
        qs[2 * tid] = __uint_as_float(u << 16) * QSCALE;
        qs[2 * tid + 1] = __uint_as_float(u & 0xFFFF0000u) * QSCALE;
    }
    if (tid < 64) {
        int kk = -1;
        if (tid < total) {
            if (tid < n_mem)
                kk = ms + tid;
            else if (tid < n_mem + 4)
                kk = 15 + i * 4 + (tid - n_mem);
            else
                kk = 79 + us + (tid - n_mem - 4);
        }
        kks[tid] = kk;
    }
    __syncthreads();

#pragma unroll
    for (int rep = 0; rep < 2; ++rep) {
        int p = rep * 256 + tid;
        int h = p >> 6, j = p & 63;
        int kk = kks[j];
        float s = NEGV;
        if (kk >= 0 && kk < klen) {
            const int4* kr = (const int4*)&QKV[(size_t)(kk * NB + b) * 1536 + 512 + h * DH];
            const float* qh = &qs[h * DH];
            float accd = 0.f;
#pragma unroll
            for (int c = 0; c < 8; ++c) {
                int4 kv = kr[c];
                const int uu[4] = {kv.x, kv.y, kv.z, kv.w};
#pragma unroll
                for (int jj = 0; jj < 4; ++jj) {
                    float lo = __uint_as_float(((unsigned)uu[jj]) << 16);
                    float hi = __uint_as_float(((unsigned)uu[jj]) & 0xFFFF0000u);
                    accd = fmaf(lo, qh[c * 8 + jj * 2], accd);
                    accd = fmaf(hi, qh[c * 8 + jj * 2 + 1], accd);
                }
            }
            s = accd;
        }
        sc[h][j] = s;
    }
    __syncthreads();

    {
        int wv = tid >> 6, lane = tid & 63;
#pragma unroll
        for (int hh = 0; hh < 2; ++hh) {
            int h = wv + hh * 4;
            float s = sc[h][lane];
            float m = s;
#pragma unroll
            for (int off = 32; off; off >>= 1) m = fmaxf(m, __shfl_xor(m, off));
            float p = __expf(s - m);
            float sum = p;
#pragma unroll
            for (int off = 32; off; off >>= 1) sum += __shfl_xor(sum, off);
            sc[h][lane] = p / sum;
        }
    }
    __syncthreads();

    {
        int h = tid >> 5;
        const float* ph = sc[h];
        float a0 = 0.f, a1 = 0.f;
        const unsigned short* vbase = QKV + (size_t)b * 1536 + 1024 + 2 * tid;
#pragma unroll 4
        for (int j = 0; j < total; ++j) {
            int kkj = kks[j];
            unsigned int u = *(const unsigned int*)&vbase[(size_t)kkj * (NB * 1536)];
            float p = ph[j];
            a0 = fmaf(p, __uint_as_float(u << 16), a0);
            a1 = fmaf(p, __uint_as_float(u & 0xFFFF0000u), a1);
        }
        unsigned int o = ((unsigned int)f2bf(a0)) | (((unsigned int)f2bf(a1)) << 16);
        *(unsigned int*)&ATT[(size_t)(qrow * NB + b) * D + 2 * tid] = o;
    }
}

// ---------------- final LN (width 1024) with permuted output ----------------
__global__ __launch_bounds__(256) void final_ln_k(const float* __restrict__ Yb,
                                                  const float* __restrict__ g,
                                                  const float* __restrict__ be,
                                                  float* __restrict__ out) {
    int row = blockIdx.x;
    int u = row >> 3, b = row & 7;
    const float* x = Yb + (size_t)row * OUTD;
    float v[4];
    float s = 0.f, ss = 0.f;
#pragma unroll
    for (int j = 0; j < 4; ++j) {
        v[j] = x[threadIdx.x + j * 256];
        s += v[j];
        ss = fmaf(v[j], v[j], ss);
    }
#pragma unroll
    for (int off = 32; off; off >>= 1) {
        s += __shfl_xor(s, off);
        ss += __shfl_xor(ss, off);
    }
    __shared__ float rs_[4], rss_[4];
    int w = threadIdx.x >> 6;
    if ((threadIdx.x & 63) == 0) {
        rs_[w] = s;
        rss_[w] = ss;
    }
    __syncthreads();
    s = rs_[0] + rs_[1] + rs_[2] + rs_[3];
    ss = rss_[0] + rss_[1] + rss_[2] + rss_[3];
    float mean = s * (1.f / OUTD);
    float var = ss * (1.f / OUTD) - mean * mean;
    float rstd = rsqrtf(var + 1e-5f);
    float* o = out + ((size_t)(b * 256 + u)) * OUTD;
#pragma unroll
    for (int j = 0; j < 4; ++j) {
        int col = threadIdx.x + j * 256;
        o[col] = (v[j] - mean) * rstd * g[col] + be[col];
    }
}

extern "C" void kernel_launch(void* const* d_in, const int* in_sizes, int n_in, void* d_out,
                              int out_size, void* d_ws, size_t ws_size, hipStream_t stream) {
    (void)in_sizes;
    (void)n_in;
    (void)out_size;
    (void)ws_size;
    const float* input = (const float*)d_in[0];
    const int* lengths = (const int*)d_in[1];
    const float* w_in = (const float*)d_in[2];
    const float* ln_in_g = (const float*)d_in[3];
    const float* ln_in_b = (const float*)d_in[4];
    const float* wq = (const float*)d_in[5];
    const float* bq = (const float*)d_in[6];
    const float* wk = (const float*)d_in[7];
    const float* bk = (const float*)d_in[8];
    const float* wv = (const float*)d_in[9];
    const float* bv = (const float*)d_in[10];
    const float* wo = (const float*)d_in[11];
    const float* bo = (const float*)d_in[12];
    const float* ff_g = (const float*)d_in[13];
    const float* ff_b = (const float*)d_in[14];
    const float* w1 = (const float*)d_in[15];
    const float* b1 = (const float*)d_in[16];
    const float* w2 = (const float*)d_in[17];
    const float* b2 = (const float*)d_in[18];
    const float* lo_g = (const float*)d_in[19];
    const float* lo_b = (const float*)d_in[20];
    const float* w_out = (const float*)d_in[21];
    const float* b_out = (const float*)d_in[22];
    const float* lng = (const float*)d_in[23];
    const float* lnb = (const float*)d_in[24];
    float* out = (float*)d_out;

    char* wsc = (char*)d_ws;
    size_t off = 0;
    auto alloc = [&](size_t bytes) {
        char* p = wsc + off;
        off += (bytes + 255) & ~(size_t)255;
        return p;
    };
    unsigned short* ACT16 = (unsigned short*)alloc(2808ULL * 512 * 2);
    unsigned short* ATT16 = (unsigned short*)alloc(2688ULL * 512 * 2);
    unsigned short* HB16 = (unsigned short*)alloc(2560ULL * 2048 * 2);
    unsigned short* QKVB = (unsigned short*)alloc(2808ULL * 1536 * 2);
    float* SB = (float*)alloc(2560ULL * 512 * 4);
    unsigned short* WQKV16 = (unsigned short*)alloc(8ULL * 1536 * 512 * 2);
    unsigned short* WO16 = (unsigned short*)alloc(8ULL * 512 * 512 * 2);
    unsigned short* W1T = (unsigned short*)alloc(8ULL * 2048 * 512 * 2);
    unsigned short* W2T = (unsigned short*)alloc(8ULL * 512 * 2048 * 2);
    unsigned short* WOUT16 = (unsigned short*)alloc(1024ULL * 512 * 2);
    float* BQKV = (float*)alloc(8ULL * 1536 * 4);
    int* LRW = (int*)alloc(64);

    unsigned short* MEMS16 = ACT16;               // 120 rows
    unsigned short* LNB16 = ACT16 + 120 * 512;    // 2560 rows
    unsigned short* SUMB16 = ACT16 + 2680 * 512;  // 128 rows
    float* XB = (float*)QKVB;    // init-time alias
    float* OUTB = (float*)QKVB;  // post-attention alias
    float* HBf = (float*)QKVB;   // final-proj alias

    lr_k<<<1, 64, 0, stream>>>(lengths, LRW, out + (size_t)NB * 256 * 1024);
    convw_all_k<<<LAYERS * 3072 + 512, 256, 0, stream>>>(wq, wk, wv, wo, w1, w2, bq, bk, bv,
                                                         w_out, WQKV16, WO16, W1T, W2T, WOUT16,
                                                         BQKV);
    inproj_k<<<TR * NB, 128, 0, stream>>>(input, w_in, XB);
    initstate_k<<<SROWS * NB, 256, 0, stream>>>(XB, SB);
    mems0_k<<<15 * NB, 256, 0, stream>>>(XB, MEMS16);

    for (int l = 0; l < LAYERS; ++l) {
        ln_k<<<SROWS * NB, 256, 0, stream>>>(SB, LNB16, SB, ln_in_g + l * D, ln_in_b + l * D, 0);
        summary_k<<<NSEG * NB, 256, 0, stream>>>(LNB16, SUMB16);
        // fused QKV: A = [MEMS][LN][SUM] (2808 rows), N = 1536
        gemm16_k<<<dim3(24, 44, 1), 256, 0, stream>>>(ACT16, WQKV16 + (size_t)l * 1536 * 512,
                                                      BQKV + l * 1536, QKVB, 2808, 1536, 512, 512,
                                                      4);
        attn_k<<<dim3(QN, NB), 256, 0, stream>>>(QKVB, ATT16, LRW);
        gemm16_k<<<dim3(8, 42, 1), 256, 0, stream>>>(ATT16, WO16 + (size_t)l * 512 * 512,
                                                     bo + l * D, OUTB, QN * NB, D, D, 512, 0);
        ln_res_k<<<(SROWS + 15) * NB, 256, 0, stream>>>(OUTB, SB, MEMS16, LNB16, ff_g + l * D,
                                                        ff_b + l * D);
        gemm16_k<<<dim3(32, 40, 1), 256, 0, stream>>>(LNB16, W1T + (size_t)l * 2048 * 512,
                                                      b1 + l * FFN_D, HB16, SROWS * NB, FFN_D,
                                                      512, 512, 1 | 4);
        gemm16_k<<<dim3(8, 40, 4), 256, 0, stream>>>(HB16, W2T + (size_t)l * 512 * 2048,
                                                     b2 + l * D, SB, SROWS * NB, D, FFN_D, 512,
                                                     8);
        ln_k<<<SROWS * NB, 256, 0, stream>>>(SB, LNB16, SB, lo_g + l * D, lo_b + l * D, 1);
    }
    // final projection of utt rows (LNB16 rows 64*NB ..) then LN -> out
    gemm16_k<<<dim3(16, 32, 1), 256, 0, stream>>>(LNB16 + (size_t)RT * NB * D, WOUT16, b_out,
                                                  HBf, UU * NB, OUTD, 512, 512, 0);
    final_ln_k<<<UU * NB, 256, 0, stream>>>(HBf, lng, lnb, out);
}